// Round 15
// baseline (910.527 us; speedup 1.0000x reference)
//
#include <hip/hip_runtime.h>
#include <hip/hip_cooperative_groups.h>

namespace cg = cooperative_groups;

#define HD 192
#define FD0 128
#define NG 256
#define BNEPS 1e-5f

#define STAT_S  1048576.0f        // 2^20 fixed-point scale for BN stats
#define STAT_IS (1.0f / 1048576.0f)
#define POOL_S  65536.0f          // 2^16 fixed-point scale for pooling
#define POOL_IS (1.0f / 65536.0f)

#define GRID 256
#define TPB  512
#define SMEM_BYTES 148992         // 192*384*2 (panel) + 2*192*4 (BN tables)

typedef unsigned short u16;
typedef __attribute__((ext_vector_type(8))) short bf16x8;
typedef __attribute__((ext_vector_type(4))) float f32x4;

static inline int idiv(int a, int b) { return (a + b - 1) / b; }

__device__ __forceinline__ float b2f(u16 u) {
    unsigned int v = ((unsigned int)u) << 16;
    return __builtin_bit_cast(float, v);
}
__device__ __forceinline__ u16 f2b(float f) {
    unsigned int x = __builtin_bit_cast(unsigned int, f);
    return (u16)((x + 0x7FFFu + ((x >> 16) & 1u)) >> 16);   // RNE
}

__device__ __forceinline__ void bn_params(const long long* __restrict__ statsq,
    const float* __restrict__ gamma, const float* __restrict__ beta,
    int N, int c, float& sc, float& sh)
{
    const float inv = 1.0f / (float)N;
    const float sum = (float)statsq[c] * STAT_IS;
    const float sq  = (float)statsq[HD + c] * STAT_IS;
    const float mu  = sum * inv;
    const float var = sq * inv - mu * mu;
    const float s   = gamma[c] * rsqrtf(var + BNEPS);
    sc = s; sh = beta[c] - mu * s;
}

__device__ __forceinline__ void async_cp16(const void* g, void* l) {
    __builtin_amdgcn_global_load_lds(
        (const __attribute__((address_space(1))) unsigned int*)g,
        (__attribute__((address_space(3))) unsigned int*)l, 16, 0, 0);
}

struct MegaArgs {
    const float* x; const int* src; const int* dst; const int* batch;
    const float* w_rel0; const float* b_rel0; const float* w_root0;
    const float* w_rel; const float* b_rel; const float* w_root;
    const float* bn_g; const float* bn_b;
    const float* hw1; const float* hb1; const float* hw2; const float* hb2;
    const float* ow; const float* ob; float* out;
    u16* xb; u16* h; u16* aggb; u16* wp0; u16* wp123;
    float* w1t; float* w2t; long long* statsq4; int* gsumq;
    int* rowptr; int* deg; int* psum; int* eidx;
    int N, E, M;
};

// ------- pack [Wr | Wt] bf16, MFMA-frag chunk order: [chunk][f12][kg][c][j] ---
__device__ __forceinline__ void pack_one(const float* __restrict__ wr,
    const float* __restrict__ wt, u16* __restrict__ out, int K, int idx)
{
    const int j  = idx & 7;
    const int t  = idx >> 3;
    const int c  = t & 15;
    const int kg = (t >> 4) & 3;
    const int rest = t >> 6;
    const int fglob = rest % 12;
    const int chunk = rest / 12;
    const int col = fglob * 16 + c;
    const int k   = chunk * 32 + kg * 8 + j;
    const float v = (k < K) ? wr[(size_t)col * K + k] : wt[(size_t)col * K + (k - K)];
    out[idx] = f2b(v);
}

// ------- gather phase: wave/node grid-stride; BN+ReLU fused; fp32 acc --------
template<int FD, bool BN>
__device__ void gather_phase(const MegaArgs& a, const u16* __restrict__ hsrc,
    u16* __restrict__ aggb, const long long* __restrict__ statsq,
    const float* __restrict__ gamma, const float* __restrict__ beta,
    unsigned char* smem)
{
    constexpr int OCT = FD / 8;
    float* scs = (float*)smem;
    float* shs = scs + FD;
    const int t = threadIdx.x;
    if (BN) {
        if (t < FD) {
            float sc, sh;
            bn_params(statsq, gamma, beta, a.N, t, sc, sh);
            scs[t] = sc; shs[t] = sh;
        }
        __syncthreads();
    }
    const int lane = t & 63;
    const int half = lane >> 5;
    const int o    = lane & 31;
    const int wave = t >> 6;
    const bool act = (o < OCT);

    float scr[8], shr[8];
    if (BN && act) {
#pragma unroll
        for (int i = 0; i < 8; ++i) { scr[i] = scs[o * 8 + i]; shr[i] = shs[o * 8 + i]; }
    }

    for (int n = blockIdx.x * 8 + wave; n < a.N; n += GRID * 8) {
        const int beg = a.rowptr[n], end = a.rowptr[n + 1];
        float acc[8];
#pragma unroll
        for (int i = 0; i < 8; ++i) acc[i] = 0.f;

        auto consume = [&](uint4 v) {
            const u16* pu = (const u16*)&v;
#pragma unroll
            for (int i = 0; i < 8; ++i) {
                float f = b2f(pu[i]);
                if (BN) f = fmaxf(0.f, fmaf(f, scr[i], shr[i]));
                acc[i] += f;
            }
        };

        int j = beg + half;
        for (; j + 6 < end; j += 8) {
            const int s0 = a.eidx[j],     s1 = a.eidx[j + 2];
            const int s2 = a.eidx[j + 4], s3 = a.eidx[j + 6];
            if (act) {
                const uint4 v0 = *(const uint4*)(hsrc + (size_t)s0 * FD + o * 8);
                const uint4 v1 = *(const uint4*)(hsrc + (size_t)s1 * FD + o * 8);
                const uint4 v2 = *(const uint4*)(hsrc + (size_t)s2 * FD + o * 8);
                const uint4 v3 = *(const uint4*)(hsrc + (size_t)s3 * FD + o * 8);
                consume(v0); consume(v1); consume(v2); consume(v3);
            }
        }
        for (; j < end; j += 2) {
            const int s0 = a.eidx[j];
            if (act) consume(*(const uint4*)(hsrc + (size_t)s0 * FD + o * 8));
        }
#pragma unroll
        for (int i = 0; i < 8; ++i) acc[i] += __shfl_xor(acc[i], 32);

        if (half == 0 && act) {
            u16 ov[8];
#pragma unroll
            for (int i = 0; i < 8; ++i) ov[i] = f2b(acc[i]);
            *(uint4*)(aggb + (size_t)n * FD + o * 8) = *(uint4*)ov;
        }
    }
}

// ------- gemm phase: 256-row tile per block; panel LDS; ring-4 A prefetch ----
template<int K1, int K2, bool BN>
__device__ void gemm_phase(const MegaArgs& a, const u16* __restrict__ A1,
    const u16* A2, const u16* __restrict__ Wb, const float* __restrict__ bias,
    u16* Hout, long long* __restrict__ statsq_out,
    const long long* __restrict__ statsq_in, const float* __restrict__ gamma,
    const float* __restrict__ beta, unsigned char* smem)
{
    constexpr int KC  = K1 + K2;
    constexpr int NC  = KC / 32;
    constexpr int NC1 = K1 / 32;
    u16* bsh = (u16*)smem;
    float* scs = (float*)(smem + (size_t)HD * KC * 2);
    float* shs = scs + K2;

    const int ntiles = (a.N + 255) >> 8;
    if (blockIdx.x >= ntiles) return;     // block-uniform: safe w.r.t. barriers

    const int tid  = threadIdx.x;
    const int wave = tid >> 6, lane = tid & 63;
    const int c = lane & 15, kg = lane >> 4;
    const int row0 = blockIdx.x * 256 + wave * 32;

    {   // stage whole panel linearly
        constexpr int NST = (HD * KC) / (TPB * 8);
        const u16* wsrc = Wb + tid * 8;
        u16* ldst = bsh + tid * 8;
#pragma unroll
        for (int i = 0; i < NST; ++i)
            async_cp16(wsrc + i * 4096, ldst + i * 4096);
    }
    if (BN) {
        if (tid < K2) {
            float sc, sh;
            bn_params(statsq_in, gamma, beta, a.N, tid, sc, sh);
            scs[tid] = sc; shs[tid] = sh;
        }
    }

    int arc[2];
#pragma unroll
    for (int m = 0; m < 2; ++m) {
        const int r = row0 + m * 16 + c;
        arc[m] = r < a.N ? r : a.N - 1;
    }

    f32x4 acc[2][12];
#pragma unroll
    for (int m = 0; m < 2; ++m)
#pragma unroll
        for (int f = 0; f < 12; ++f) acc[m][f] = (f32x4){0.f, 0.f, 0.f, 0.f};

    auto aload = [&](int ch, bf16x8* d) {
#pragma unroll
        for (int m = 0; m < 2; ++m) {
            const u16* p = (ch < NC1)
                ? (A1 + (size_t)arc[m] * K1 + ch * 32 + kg * 8)
                : (A2 + (size_t)arc[m] * K2 + (ch - NC1) * 32 + kg * 8);
            d[m] = *(const bf16x8*)p;
        }
    };

    bf16x8 ring[4][2];
#pragma unroll
    for (int p = 0; p < 4; ++p)
        if (p < NC) aload(p, ring[p]);

    __syncthreads();      // drains staging; BN tables visible

#pragma unroll
    for (int ch = 0; ch < NC; ++ch) {
        bf16x8 av[2] = { ring[ch & 3][0], ring[ch & 3][1] };
        if (ch + 4 < NC) aload(ch + 4, ring[ch & 3]);
        if (BN && ch >= NC1) {
            const int k0 = (ch - NC1) * 32 + kg * 8;
            const float4 s0 = *(const float4*)&scs[k0];
            const float4 s1 = *(const float4*)&scs[k0 + 4];
            const float4 h0 = *(const float4*)&shs[k0];
            const float4 h1 = *(const float4*)&shs[k0 + 4];
            const float scv[8] = {s0.x,s0.y,s0.z,s0.w,s1.x,s1.y,s1.z,s1.w};
            const float shv[8] = {h0.x,h0.y,h0.z,h0.w,h1.x,h1.y,h1.z,h1.w};
#pragma unroll
            for (int m = 0; m < 2; ++m) {
                const u16* pa = (const u16*)&av[m];
                u16 tv[8];
#pragma unroll
                for (int i = 0; i < 8; ++i)
                    tv[i] = f2b(fmaxf(0.f, fmaf(b2f(pa[i]), scv[i], shv[i])));
                av[m] = *(bf16x8*)tv;
            }
        }
#pragma unroll
        for (int f = 0; f < 12; ++f) {
            const bf16x8 b = *(const bf16x8*)&bsh[ch * 6144 + f * 512 + kg * 128 + c * 8];
            acc[0][f] = __builtin_amdgcn_mfma_f32_16x16x32_bf16(av[0], b, acc[0][f], 0, 0, 0);
            acc[1][f] = __builtin_amdgcn_mfma_f32_16x16x32_bf16(av[1], b, acc[1][f], 0, 0, 0);
        }
    }

    // ---- epilogue: bias + store + BN partial sums ----
    float s1v[12], s2v[12];
#pragma unroll
    for (int f = 0; f < 12; ++f) { s1v[f] = 0.f; s2v[f] = 0.f; }

#pragma unroll
    for (int f = 0; f < 12; ++f) {
        const int col = f * 16 + c;
        const float bv = bias[col];
#pragma unroll
        for (int m = 0; m < 2; ++m)
#pragma unroll
            for (int r = 0; r < 4; ++r) {
                const int orow = row0 + m * 16 + kg * 4 + r;
                if (orow < a.N) {
                    const float v = acc[m][f][r] + bv;
                    s1v[f] += v;
                    s2v[f] += v * v;
                    Hout[(size_t)orow * HD + col] = f2b(v);
                }
            }
    }
#pragma unroll
    for (int f = 0; f < 12; ++f) {
        s1v[f] += __shfl_xor(s1v[f], 16); s1v[f] += __shfl_xor(s1v[f], 32);
        s2v[f] += __shfl_xor(s2v[f], 16); s2v[f] += __shfl_xor(s2v[f], 32);
    }
    __syncthreads();                       // all waves done with bsh
    float* red = (float*)bsh;
    if (kg == 0) {
#pragma unroll
        for (int f = 0; f < 12; ++f) {
            red[wave * HD + f * 16 + c]          = s1v[f];
            red[8 * HD + wave * HD + f * 16 + c] = s2v[f];
        }
    }
    __syncthreads();
    if (tid < HD) {
        float a1 = 0.f, a2 = 0.f;
#pragma unroll
        for (int w = 0; w < 8; ++w) {
            a1 += red[w * HD + tid];
            a2 += red[8 * HD + w * HD + tid];
        }
        atomicAdd((unsigned long long*)&statsq_out[tid],
                  (unsigned long long)(long long)llrintf(a1 * STAT_S));
        atomicAdd((unsigned long long*)&statsq_out[HD + tid],
                  (unsigned long long)(long long)llrintf(a2 * STAT_S));
    }
}

// ------------------------------ the mega kernel ------------------------------
__global__ __launch_bounds__(TPB, 2) void mega(MegaArgs a)
{
    cg::grid_group grid = cg::this_grid();
    __shared__ __align__(16) unsigned char smem[SMEM_BYTES];

    const int tid  = threadIdx.x;
    const int gtid = blockIdx.x * TPB + tid;
    const int GT   = GRID * TPB;

    // ---- P0: zero buffers ∥ convert x ∥ pack weights ∥ transpose head ----
    for (int i = gtid; i < a.N; i += GT) a.deg[i] = 0;
    for (int i = gtid; i < 4 * 2 * HD; i += GT) a.statsq4[i] = 0;
    for (int i = gtid; i < NG * HD; i += GT) a.gsumq[i] = 0;
    {
        const int n4 = a.N * FD0 / 4;
        for (int i = gtid; i < n4; i += GT) {
            const float4 v = ((const float4*)a.x)[i];
            u16 o[4] = { f2b(v.x), f2b(v.y), f2b(v.z), f2b(v.w) };
            ((ushort4*)a.xb)[i] = *(ushort4*)o;
        }
    }
    {
        const int T0 = HD * 2 * FD0, T1 = HD * 2 * HD, TW = HD * HD;
        const int TT = T0 + 3 * T1 + 2 * TW;
        for (int ii = gtid; ii < TT; ii += GT) {
            int idx = ii;
            if (idx < T0) { pack_one(a.w_rel0, a.w_root0, a.wp0, FD0, idx); continue; }
            idx -= T0;
            if (idx < 3 * T1) {
                const int li = idx / T1;
                const int r  = idx - li * T1;
                pack_one(a.w_rel + (size_t)li * HD * HD, a.w_root + (size_t)li * HD * HD,
                         a.wp123 + (size_t)li * T1, HD, r);
                continue;
            }
            idx -= 3 * T1;
            const float* w = (idx < TW) ? a.hw1 : a.hw2;
            float*       o = (idx < TW) ? a.w1t : a.w2t;
            const int r = (idx < TW) ? idx : idx - TW;
            const int t = r % HD, k = r / HD;
            o[r] = w[(size_t)t * HD + k];
        }
    }
    grid.sync();

    // ---- P1: histogram of dst ----
    for (int e = gtid; e < a.E; e += GT)
        atomicAdd(&a.deg[a.dst[e]], 1);
    grid.sync();

    // ---- P2: per-chunk partial sums ----
    {
        int* s = (int*)smem;
        const int i = blockIdx.x * 256 + tid;
        if (tid < 256)
            s[tid] = (blockIdx.x < a.M && i < a.N) ? a.deg[i] : 0;
        __syncthreads();
        for (int off = 128; off > 0; off >>= 1) {
            if (tid < off) s[tid] += s[tid + off];
            __syncthreads();
        }
        if (tid == 0 && blockIdx.x < a.M) a.psum[blockIdx.x] = s[0];
    }
    grid.sync();

    // ---- P3: scan chunk sums (block 0) ----
    {
        int* s = (int*)smem;
        if (tid < 256)
            s[tid] = (blockIdx.x == 0 && tid < a.M) ? a.psum[tid] : 0;
        __syncthreads();
        for (int off = 1; off < 256; off <<= 1) {
            const int u = (tid >= off && tid < 256) ? s[tid - off] : 0;
            __syncthreads();
            if (tid < 256) s[tid] += u;
            __syncthreads();
        }
        if (blockIdx.x == 0 && tid < a.M) a.psum[tid] = (tid == 0) ? 0 : s[tid - 1];
    }
    grid.sync();

    // ---- P4: expand to rowptr + cursor ----
    {
        int* s = (int*)smem;
        const int i = blockIdx.x * 256 + tid;
        const bool inb = (blockIdx.x < a.M) && (tid < 256) && (i < a.N);
        const int v = inb ? a.deg[i] : 0;
        if (tid < 256) s[tid] = v;
        __syncthreads();
        for (int off = 1; off < 256; off <<= 1) {
            const int u = (tid >= off && tid < 256) ? s[tid - off] : 0;
            __syncthreads();
            if (tid < 256) s[tid] += u;
            __syncthreads();
        }
        if (inb) {
            const int base = a.psum[blockIdx.x] + s[tid] - v;
            a.rowptr[i] = base;
            a.deg[i]    = base;               // fill cursor
            if (i == a.N - 1) a.rowptr[a.N] = a.E;
        }
    }
    grid.sync();

    // ---- P5: fill buckets ----
    for (int e = gtid; e < a.E; e += GT) {
        const int p = atomicAdd(&a.deg[a.dst[e]], 1);
        a.eidx[p] = a.src[e];
    }
    grid.sync();

    // ---- layer 0 ----
    gather_phase<FD0, false>(a, a.xb, a.aggb, nullptr, nullptr, nullptr, smem);
    grid.sync();
    gemm_phase<FD0, FD0, false>(a, a.aggb, a.xb, a.wp0, a.b_rel0, a.h,
                                a.statsq4, nullptr, nullptr, nullptr, smem);
    grid.sync();

    // ---- layers 1..3 ----
#pragma unroll 1
    for (int i = 0; i < 3; ++i) {
        const long long* sin  = a.statsq4 + (size_t)i * 2 * HD;
        long long*       sout = a.statsq4 + (size_t)(i + 1) * 2 * HD;
        const float* g = a.bn_g + (size_t)i * HD;
        const float* b = a.bn_b + (size_t)i * HD;
        gather_phase<HD, true>(a, a.h, a.aggb, sin, g, b, smem);
        grid.sync();
        gemm_phase<HD, HD, true>(a, a.aggb, a.h,
                                 a.wp123 + (size_t)i * HD * 2 * HD,
                                 a.b_rel + (size_t)i * HD, a.h,
                                 sout, sin, g, b, smem);
        grid.sync();
    }

    // ---- pool partials (BN(3) fused) ----
    if (blockIdx.x < a.M) {
        float* scs = (float*)smem;
        float* shs = scs + HD;
        if (tid < HD) {
            float sc, sh;
            bn_params(a.statsq4 + 3 * 2 * (size_t)HD, a.bn_g + 3 * (size_t)HD,
                      a.bn_b + 3 * (size_t)HD, a.N, tid, sc, sh);
            scs[tid] = sc; shs[tid] = sh;
        }
        __syncthreads();
        if (tid < HD) {
            const int rl  = tid / 24;
            const int oct = tid % 24;
            const int r0  = blockIdx.x * 256;
            const int rend = (r0 + 256 < a.N) ? r0 + 256 : a.N;
            float scr[8], shr[8];
#pragma unroll
            for (int i = 0; i < 8; ++i) { scr[i] = scs[oct * 8 + i]; shr[i] = shs[oct * 8 + i]; }
            float facc[8];
#pragma unroll
            for (int i = 0; i < 8; ++i) facc[i] = 0.f;
            int cur = -1;
            for (int r = r0 + rl; r < rend; r += 8) {
                const int bb = a.batch[r];
                if (bb != cur) {
                    if (cur >= 0) {
                        int* q = a.gsumq + (size_t)cur * HD + oct * 8;
#pragma unroll
                        for (int i = 0; i < 8; ++i)
                            atomicAdd(&q[i], __float2int_rn(facc[i] * POOL_S));
                    }
#pragma unroll
                    for (int i = 0; i < 8; ++i) facc[i] = 0.f;
                    cur = bb;
                }
                const uint4 pv = *(const uint4*)(a.h + (size_t)r * HD + oct * 8);
                const u16* pu = (const u16*)&pv;
#pragma unroll
                for (int i = 0; i < 8; ++i)
                    facc[i] += fmaxf(0.f, fmaf(b2f(pu[i]), scr[i], shr[i]));
            }
            if (cur >= 0) {
                int* q = a.gsumq + (size_t)cur * HD + oct * 8;
#pragma unroll
                for (int i = 0; i < 8; ++i)
                    atomicAdd(&q[i], __float2int_rn(facc[i] * POOL_S));
            }
        }
    }
    grid.sync();

    // ---- head: one graph per block ----
    {
        float* gv = (float*)smem;
        float* h1 = gv + HD;
        float* h2 = h1 + HD;
        const int g = blockIdx.x;
        if (g < NG) {
            int lo = 0, hi = a.N;
            while (lo < hi) { int m = (lo + hi) >> 1; if (a.batch[m] < g) lo = m + 1; else hi = m; }
            const int start = lo;
            hi = a.N;
            while (lo < hi) { int m = (lo + hi) >> 1; if (a.batch[m] < g + 1) lo = m + 1; else hi = m; }
            const int end = lo;
            const float cnt = fmaxf((float)(end - start), 1.0f);

            if (tid < HD)
                gv[tid] = (float)a.gsumq[(size_t)g * HD + tid] * POOL_IS / cnt;
            __syncthreads();
            if (tid < HD) {
                float acc = a.hb1[tid];
#pragma unroll 4
                for (int k = 0; k < HD; ++k)
                    acc = fmaf(gv[k], a.w1t[k * HD + tid], acc);
                h1[tid] = fmaxf(acc, 0.f);
            }
            __syncthreads();
            if (tid < HD) {
                float acc = a.hb2[tid];
#pragma unroll 4
                for (int k = 0; k < HD; ++k)
                    acc = fmaf(h1[k], a.w2t[k * HD + tid], acc);
                h2[tid] = acc * a.ow[tid];
            }
            __syncthreads();
            if (tid < 64) {
                float s = h2[tid] + h2[tid + 64] + h2[tid + 128];
#pragma unroll
                for (int d = 1; d < 64; d <<= 1) s += __shfl_xor(s, d);
                if (tid == 0) a.out[g] = s + a.ob[0];
            }
        }
    }
}

extern "C" void kernel_launch(void* const* d_in, const int* in_sizes, int n_in,
                              void* d_out, int out_size, void* d_ws, size_t ws_size,
                              hipStream_t stream)
{
    const int N = in_sizes[0] / FD0;
    const int E = in_sizes[1] / 2;
    const int M = idiv(N, 256);

    char* ws = (char*)d_ws;
    size_t off = 0;
    u16*   xb   = (u16*)(ws + off);   off += (size_t)N * FD0 * 2;
    u16*   h    = (u16*)(ws + off);   off += (size_t)N * HD * 2;
    u16*   aggb = (u16*)(ws + off);   off += (size_t)N * HD * 2;
    u16*   wp0  = (u16*)(ws + off);   off += (size_t)HD * 2 * FD0 * 2;
    u16*   wp123= (u16*)(ws + off);   off += (size_t)3 * HD * 2 * HD * 2;
    off = (off + 15) & ~(size_t)15;
    float* w1t = (float*)(ws + off); off += (size_t)HD * HD * 4;
    float* w2t = (float*)(ws + off); off += (size_t)HD * HD * 4;
    long long* statsq4 = (long long*)(ws + off); off += 4 * 2 * HD * sizeof(long long);
    int*   gsumq  = (int*)(ws + off); off += (size_t)NG * HD * 4;
    int*   rowptr = (int*)(ws + off); off += (size_t)(N + 1) * 4;
    int*   deg    = (int*)(ws + off); off += (size_t)N * 4;
    int*   psum   = (int*)(ws + off); off += (size_t)M * 4;
    int*   eidx   = (int*)(ws + off); off += (size_t)E * 4;

    MegaArgs a;
    a.x = (const float*)d_in[0];
    a.src = (const int*)d_in[1];
    a.dst = (const int*)d_in[1] + E;
    a.batch = (const int*)d_in[2];
    a.w_rel0 = (const float*)d_in[4];
    a.b_rel0 = (const float*)d_in[5];
    a.w_root0 = (const float*)d_in[6];
    a.w_rel = (const float*)d_in[7];
    a.b_rel = (const float*)d_in[8];
    a.w_root = (const float*)d_in[9];
    a.bn_g = (const float*)d_in[10];
    a.bn_b = (const float*)d_in[11];
    a.hw1 = (const float*)d_in[12];
    a.hb1 = (const float*)d_in[13];
    a.hw2 = (const float*)d_in[14];
    a.hb2 = (const float*)d_in[15];
    a.ow = (const float*)d_in[16];
    a.ob = (const float*)d_in[17];
    a.out = (float*)d_out;
    a.xb = xb; a.h = h; a.aggb = aggb; a.wp0 = wp0; a.wp123 = wp123;
    a.w1t = w1t; a.w2t = w2t; a.statsq4 = statsq4; a.gsumq = gsumq;
    a.rowptr = rowptr; a.deg = deg; a.psum = psum; a.eidx = eidx;
    a.N = N; a.E = E; a.M = M;

    void* kargs[] = { &a };
    hipLaunchCooperativeKernel((const void*)mega, dim3(GRID), dim3(TPB),
                               kargs, 0, stream);
}

// Round 16
// 478.170 us; speedup vs baseline: 1.9042x; 1.9042x over previous
//
#include <hip/hip_runtime.h>

#define HD 192
#define FD0 128
#define NG 256
#define BNEPS 1e-5f

#define STAT_S  1048576.0f        // 2^20 fixed-point scale for BN stats
#define STAT_IS (1.0f / 1048576.0f)
#define POOL_S  65536.0f          // 2^16 fixed-point scale for pooling
#define POOL_IS (1.0f / 65536.0f)

typedef unsigned short u16;
typedef __attribute__((ext_vector_type(8))) short bf16x8;
typedef __attribute__((ext_vector_type(4))) float f32x4;

static inline int idiv(int a, int b) { return (a + b - 1) / b; }

__device__ __forceinline__ float b2f(u16 u) {
    unsigned int v = ((unsigned int)u) << 16;
    return __builtin_bit_cast(float, v);
}
__device__ __forceinline__ u16 f2b(float f) {
    unsigned int x = __builtin_bit_cast(unsigned int, f);
    return (u16)((x + 0x7FFFu + ((x >> 16) & 1u)) >> 16);   // RNE
}

// BN scale/shift from fixed-point sum/sumsq (statsq layout: [HD sum][HD sumsq])
__device__ __forceinline__ void bn_params(const long long* __restrict__ statsq,
    const float* __restrict__ gamma, const float* __restrict__ beta,
    int N, int c, float& sc, float& sh)
{
    const float inv = 1.0f / (float)N;
    const float sum = (float)statsq[c] * STAT_IS;
    const float sq  = (float)statsq[HD + c] * STAT_IS;
    const float mu  = sum * inv;
    const float var = sq * inv - mu * mu;
    const float s   = gamma[c] * rsqrtf(var + BNEPS);
    sc = s; sh = beta[c] - mu * s;
}

// async global->LDS, 16B per lane; LDS dest = uniform base + lane*16
__device__ __forceinline__ void async_cp16(const void* g, void* l) {
    __builtin_amdgcn_global_load_lds(
        (const __attribute__((address_space(1))) unsigned int*)g,
        (__attribute__((address_space(3))) unsigned int*)l, 16, 0, 0);
}

// ---------------- x fp32 -> bf16 ----------------
__global__ __launch_bounds__(256) void convert_bf16(const float* __restrict__ in,
                                                    u16* __restrict__ out, int n4)
{
    const int i = blockIdx.x * 256 + threadIdx.x;
    if (i >= n4) return;
    const float4 v = ((const float4*)in)[i];
    u16 o[4] = { f2b(v.x), f2b(v.y), f2b(v.z), f2b(v.w) };
    ((ushort4*)out)[i] = *(ushort4*)o;
}

// ------- pack [Wr | Wt] bf16, MFMA-frag chunk order: [chunk][f12][kg][c][j] ---
__device__ __forceinline__ void pack_one(const float* __restrict__ wr,
    const float* __restrict__ wt, u16* __restrict__ out, int K, int idx)
{
    const int j  = idx & 7;
    const int t  = idx >> 3;
    const int c  = t & 15;
    const int kg = (t >> 4) & 3;
    const int rest = t >> 6;
    const int fglob = rest % 12;
    const int chunk = rest / 12;
    const int col = fglob * 16 + c;
    const int k   = chunk * 32 + kg * 8 + j;
    const float v = (k < K) ? wr[(size_t)col * K + k] : wt[(size_t)col * K + (k - K)];
    out[idx] = f2b(v);
}

// all weight packs + head transposes in ONE launch
__global__ __launch_bounds__(256) void pack_fuse(const float* __restrict__ wr0,
    const float* __restrict__ wt0, const float* __restrict__ w_rel,
    const float* __restrict__ w_root, const float* __restrict__ hw1,
    const float* __restrict__ hw2, u16* __restrict__ wp0,
    u16* __restrict__ wp123, float* __restrict__ w1t, float* __restrict__ w2t)
{
    const int T0 = HD * 2 * FD0;     // 49152
    const int T1 = HD * 2 * HD;      // 73728
    const int TW = HD * HD;          // 36864
    int idx = blockIdx.x * 256 + threadIdx.x;
    if (idx < T0) { pack_one(wr0, wt0, wp0, FD0, idx); return; }
    idx -= T0;
    if (idx < 3 * T1) {
        const int li = idx / T1;
        const int r  = idx - li * T1;
        pack_one(w_rel + (size_t)li * HD * HD, w_root + (size_t)li * HD * HD,
                 wp123 + (size_t)li * T1, HD, r);
        return;
    }
    idx -= 3 * T1;
    if (idx >= 2 * TW) return;
    const float* w = (idx < TW) ? hw1 : hw2;
    float*       o = (idx < TW) ? w1t : w2t;
    const int r = (idx < TW) ? idx : idx - TW;
    const int t = r % HD, k = r / HD;
    o[r] = w[(size_t)t * HD + k];
}

// ---------------- CSR build ----------------
__global__ __launch_bounds__(256) void hist_kernel(const int* __restrict__ dst,
                                                   int* __restrict__ deg, int E)
{
    const int e = blockIdx.x * 256 + threadIdx.x;
    if (e < E) atomicAdd(&deg[dst[e]], 1);
}

__global__ __launch_bounds__(256) void scan_partial(const int* __restrict__ deg,
                                                    int* __restrict__ psum, int N)
{
    __shared__ int s[256];
    const int t = threadIdx.x;
    const int i = blockIdx.x * 256 + t;
    s[t] = (i < N) ? deg[i] : 0;
    __syncthreads();
    for (int off = 128; off > 0; off >>= 1) {
        if (t < off) s[t] += s[t + off];
        __syncthreads();
    }
    if (t == 0) psum[blockIdx.x] = s[0];
}

__global__ __launch_bounds__(256) void scan_small(int* __restrict__ psum, int M)
{
    __shared__ int s[256];
    const int t = threadIdx.x;
    s[t] = (t < M) ? psum[t] : 0;
    __syncthreads();
    for (int off = 1; off < 256; off <<= 1) {
        const int u = (t >= off) ? s[t - off] : 0;
        __syncthreads();
        s[t] += u;
        __syncthreads();
    }
    if (t < M) psum[t] = (t == 0) ? 0 : s[t - 1];
}

// writes rowptr AND re-writes deg as the fill cursor (absolute base)
__global__ __launch_bounds__(256) void scan_expand(int* __restrict__ deg,
    const int* __restrict__ psum, int* __restrict__ rowptr, int N, int E)
{
    __shared__ int s[256];
    const int t = threadIdx.x;
    const int i = blockIdx.x * 256 + t;
    const int v = (i < N) ? deg[i] : 0;
    s[t] = v;
    __syncthreads();
    for (int off = 1; off < 256; off <<= 1) {
        const int u = (t >= off) ? s[t - off] : 0;
        __syncthreads();
        s[t] += u;
        __syncthreads();
    }
    if (i < N) {
        const int base = psum[blockIdx.x] + s[t] - v;   // exclusive
        rowptr[i] = base;
        deg[i]    = base;                                // cursor
    }
    if (i == N - 1) rowptr[N] = E;
}

__global__ __launch_bounds__(256) void fill_kernel(const int* __restrict__ src,
    const int* __restrict__ dst, int* __restrict__ cursor,
    int* __restrict__ eidx, int E)
{
    const int e = blockIdx.x * 256 + threadIdx.x;
    if (e >= E) return;
    const int p = atomicAdd(&cursor[dst[e]], 1);
    eidx[p] = src[e];
}

// ------- CSR gather, block-per-node, edge-slot parallel; fused BN+ReLU -------
// 256 thr = NSLOT slots x OCT octets; all edges' uint4 loads issue concurrently;
// LDS reduce over slots in fixed order (fp32, deterministic).
template<int FD, bool BN>
__global__ __launch_bounds__(256) void gather_kernel(
    const u16* __restrict__ hsrc, const int* __restrict__ rowptr,
    const int* __restrict__ eidx, u16* __restrict__ aggb, int N,
    const long long* __restrict__ statsq, const float* __restrict__ gamma,
    const float* __restrict__ beta)
{
    constexpr int OCT   = FD / 8;          // 24 (192) or 16 (128)
    constexpr int NSLOT = 256 / OCT;       // 10 (192) or 16 (128)
    __shared__ float scs[FD], shs[FD];
    __shared__ float pp[NSLOT][FD];
    const int t = threadIdx.x;
    if (BN) {
        if (t < FD) {
            float sc, sh;
            bn_params(statsq, gamma, beta, N, t, sc, sh);
            scs[t] = sc; shs[t] = sh;
        }
        __syncthreads();
    }
    const int oct  = t % OCT;
    const int slot = t / OCT;
    const int n    = blockIdx.x;
    if (n >= N) return;
    const int beg = rowptr[n], end = rowptr[n + 1];
    const bool act = (slot < NSLOT);

    float scr[8], shr[8];
    if (BN && act) {
#pragma unroll
        for (int i = 0; i < 8; ++i) { scr[i] = scs[oct * 8 + i]; shr[i] = shs[oct * 8 + i]; }
    }

    float acc[8];
#pragma unroll
    for (int i = 0; i < 8; ++i) acc[i] = 0.f;

    if (act) {
        for (int j = beg + slot; j < end; j += NSLOT) {
            const int s = eidx[j];
            const uint4 v = *(const uint4*)(hsrc + (size_t)s * FD + oct * 8);
            const u16* pu = (const u16*)&v;
#pragma unroll
            for (int i = 0; i < 8; ++i) {
                float f = b2f(pu[i]);
                if (BN) f = fmaxf(0.f, fmaf(f, scr[i], shr[i]));
                acc[i] += f;
            }
        }
#pragma unroll
        for (int i = 0; i < 8; ++i) pp[slot][oct * 8 + i] = acc[i];
    }
    __syncthreads();
    if (t < FD) {
        float s = 0.f;
#pragma unroll
        for (int r = 0; r < NSLOT; ++r) s += pp[r][t];   // fixed order
        aggb[(size_t)n * FD + t] = f2b(s);
    }
}

// -------- MFMA GEMM: 512 thr / 8 waves; block = 256 rows x 192 cols ----------
// Full B panel resident in LDS (staged once, global_load_lds); K-loop fully
// unrolled with depth-4 A register prefetch ring; BN+ReLU fused onto A2 reads.
// In-place safe: each wave reads only rows it later writes.
template<int K1, int K2, bool BN>
__global__ __launch_bounds__(512, 1) void gemm_mfma(
    const u16* __restrict__ A1, const u16* A2,
    const u16* __restrict__ Wb, const float* __restrict__ bias,
    u16* Hout, long long* __restrict__ statsq_out,
    const long long* __restrict__ statsq_in, const float* __restrict__ gamma,
    const float* __restrict__ beta, int N)
{
    constexpr int KC  = K1 + K2;
    constexpr int NC  = KC / 32;
    constexpr int NC1 = K1 / 32;
    __shared__ u16 bsh[HD * KC];          // 98KB (KC=256) / 147KB (KC=384)
    __shared__ float scs[K2], shs[K2];

    const int tid  = threadIdx.x;
    const int wave = tid >> 6, lane = tid & 63;
    const int c = lane & 15, kg = lane >> 4;
    const int row0 = blockIdx.x * 256 + wave * 32;

    {   // stage whole panel linearly (512 thr x 16B = 8KB per iter)
        constexpr int NST = (HD * KC) / (512 * 8);
        const u16* wsrc = Wb + tid * 8;
        u16* ldst = bsh + tid * 8;
#pragma unroll
        for (int i = 0; i < NST; ++i)
            async_cp16(wsrc + i * 4096, ldst + i * 4096);
    }
    if (BN) {
        if (tid < K2) {
            float sc, sh;
            bn_params(statsq_in, gamma, beta, N, tid, sc, sh);
            scs[tid] = sc; shs[tid] = sh;
        }
    }

    int arc[2];
#pragma unroll
    for (int m = 0; m < 2; ++m) {
        const int r = row0 + m * 16 + c;
        arc[m] = r < N ? r : N - 1;
    }

    f32x4 acc[2][12];
#pragma unroll
    for (int m = 0; m < 2; ++m)
#pragma unroll
        for (int f = 0; f < 12; ++f) acc[m][f] = (f32x4){0.f, 0.f, 0.f, 0.f};

    auto aload = [&](int ch, bf16x8* d) {
#pragma unroll
        for (int m = 0; m < 2; ++m) {
            const u16* p = (ch < NC1)
                ? (A1 + (size_t)arc[m] * K1 + ch * 32 + kg * 8)
                : (A2 + (size_t)arc[m] * K2 + (ch - NC1) * 32 + kg * 8);
            d[m] = *(const bf16x8*)p;
        }
    };

    bf16x8 ring[4][2];
#pragma unroll
    for (int p = 0; p < 4; ++p)
        if (p < NC) aload(p, ring[p]);

    __syncthreads();      // drains global_load_lds staging; scs/shs visible

#pragma unroll
    for (int ch = 0; ch < NC; ++ch) {
        bf16x8 a[2] = { ring[ch & 3][0], ring[ch & 3][1] };
        if (ch + 4 < NC) aload(ch + 4, ring[ch & 3]);   // refill slot
        if (BN && ch >= NC1) {                          // BN+ReLU on root frags
            const int k0 = (ch - NC1) * 32 + kg * 8;
            const float4 s0 = *(const float4*)&scs[k0];
            const float4 s1 = *(const float4*)&scs[k0 + 4];
            const float4 h0 = *(const float4*)&shs[k0];
            const float4 h1 = *(const float4*)&shs[k0 + 4];
            const float scv[8] = {s0.x,s0.y,s0.z,s0.w,s1.x,s1.y,s1.z,s1.w};
            const float shv[8] = {h0.x,h0.y,h0.z,h0.w,h1.x,h1.y,h1.z,h1.w};
#pragma unroll
            for (int m = 0; m < 2; ++m) {
                const u16* pa = (const u16*)&a[m];
                u16 tv[8];
#pragma unroll
                for (int i = 0; i < 8; ++i)
                    tv[i] = f2b(fmaxf(0.f, fmaf(b2f(pa[i]), scv[i], shv[i])));
                a[m] = *(bf16x8*)tv;
            }
        }
#pragma unroll
        for (int f = 0; f < 12; ++f) {
            const bf16x8 b = *(const bf16x8*)&bsh[ch * 6144 + f * 512 + kg * 128 + c * 8];
            acc[0][f] = __builtin_amdgcn_mfma_f32_16x16x32_bf16(a[0], b, acc[0][f], 0, 0, 0);
            acc[1][f] = __builtin_amdgcn_mfma_f32_16x16x32_bf16(a[1], b, acc[1][f], 0, 0, 0);
        }
    }

    // ---- epilogue: bias + store + BN partial sums ----
    float s1v[12], s2v[12];
#pragma unroll
    for (int f = 0; f < 12; ++f) { s1v[f] = 0.f; s2v[f] = 0.f; }

#pragma unroll
    for (int f = 0; f < 12; ++f) {
        const int col = f * 16 + c;
        const float bv = bias[col];
#pragma unroll
        for (int m = 0; m < 2; ++m)
#pragma unroll
            for (int r = 0; r < 4; ++r) {
                const int orow = row0 + m * 16 + kg * 4 + r;
                if (orow < N) {
                    const float v = acc[m][f][r] + bv;
                    s1v[f] += v;
                    s2v[f] += v * v;
                    Hout[(size_t)orow * HD + col] = f2b(v);
                }
            }
    }
#pragma unroll
    for (int f = 0; f < 12; ++f) {
        s1v[f] += __shfl_xor(s1v[f], 16); s1v[f] += __shfl_xor(s1v[f], 32);
        s2v[f] += __shfl_xor(s2v[f], 16); s2v[f] += __shfl_xor(s2v[f], 32);
    }
    __syncthreads();                       // all waves done with bsh
    float* red = (float*)bsh;              // reuse panel LDS: 2 x 8 x 192 floats
    if (kg == 0) {
#pragma unroll
        for (int f = 0; f < 12; ++f) {
            red[wave * HD + f * 16 + c]            = s1v[f];
            red[8 * HD + wave * HD + f * 16 + c]   = s2v[f];
        }
    }
    __syncthreads();
    if (tid < HD) {
        float a1 = 0.f, a2 = 0.f;
#pragma unroll
        for (int w = 0; w < 8; ++w) {
            a1 += red[w * HD + tid];
            a2 += red[8 * HD + w * HD + tid];
        }
        atomicAdd((unsigned long long*)&statsq_out[tid],
                  (unsigned long long)(long long)llrintf(a1 * STAT_S));
        atomicAdd((unsigned long long*)&statsq_out[HD + tid],
                  (unsigned long long)(long long)llrintf(a2 * STAT_S));
    }
}

// ------- parallel mean-pool partials with fused BN+ReLU -----------------------
__global__ __launch_bounds__(192) void pool_partial(const u16* __restrict__ h,
    const int* __restrict__ batch, int* __restrict__ gsumq, int N,
    const long long* __restrict__ statsq, const float* __restrict__ gamma,
    const float* __restrict__ beta)
{
    __shared__ float scs[HD], shs[HD];
    const int t = threadIdx.x;
    {
        float sc, sh;
        bn_params(statsq, gamma, beta, N, t, sc, sh);
        scs[t] = sc; shs[t] = sh;
    }
    __syncthreads();
    const int rl  = t / 24;        // 0..7
    const int oct = t % 24;        // 0..23
    const int r0  = blockIdx.x * 256;
    const int rend = (r0 + 256 < N) ? r0 + 256 : N;

    float scr[8], shr[8];
#pragma unroll
    for (int i = 0; i < 8; ++i) { scr[i] = scs[oct * 8 + i]; shr[i] = shs[oct * 8 + i]; }

    float facc[8];
#pragma unroll
    for (int i = 0; i < 8; ++i) facc[i] = 0.f;
    int cur = -1;

    for (int r = r0 + rl; r < rend; r += 8) {
        const int b = batch[r];
        if (b != cur) {
            if (cur >= 0) {
                int* q = gsumq + (size_t)cur * HD + oct * 8;
#pragma unroll
                for (int i = 0; i < 8; ++i)
                    atomicAdd(&q[i], __float2int_rn(facc[i] * POOL_S));
            }
#pragma unroll
            for (int i = 0; i < 8; ++i) facc[i] = 0.f;
            cur = b;
        }
        const uint4 pv = *(const uint4*)(h + (size_t)r * HD + oct * 8);
        const u16* pu = (const u16*)&pv;
#pragma unroll
        for (int i = 0; i < 8; ++i)
            facc[i] += fmaxf(0.f, fmaf(b2f(pu[i]), scr[i], shr[i]));
    }
    if (cur >= 0) {
        int* q = gsumq + (size_t)cur * HD + oct * 8;
#pragma unroll
        for (int i = 0; i < 8; ++i)
            atomicAdd(&q[i], __float2int_rn(facc[i] * POOL_S));
    }
}

// ------- MLP head: gv from fixed-point pool sums; coalesced weights -------
__global__ __launch_bounds__(192) void head_kernel(
    const int* __restrict__ gsumq, const int* __restrict__ batch, int N,
    const float* __restrict__ w1t, const float* __restrict__ b1,
    const float* __restrict__ w2t, const float* __restrict__ b2,
    const float* __restrict__ ow, const float* __restrict__ ob,
    float* __restrict__ out)
{
    __shared__ float gv[HD];
    __shared__ float h1[HD];
    __shared__ float h2[HD];
    const int g = blockIdx.x;
    const int t = threadIdx.x;

    int lo = 0, hi = N;
    while (lo < hi) { int m = (lo + hi) >> 1; if (batch[m] < g) lo = m + 1; else hi = m; }
    const int start = lo;
    hi = N;
    while (lo < hi) { int m = (lo + hi) >> 1; if (batch[m] < g + 1) lo = m + 1; else hi = m; }
    const int end = lo;
    const float cnt = fmaxf((float)(end - start), 1.0f);

    gv[t] = (float)gsumq[(size_t)g * HD + t] * POOL_IS / cnt;
    __syncthreads();
    {
        float acc = b1[t];
#pragma unroll 4
        for (int k = 0; k < HD; ++k)
            acc = fmaf(gv[k], w1t[k * HD + t], acc);
        h1[t] = fmaxf(acc, 0.f);
    }
    __syncthreads();
    {
        float acc = b2[t];
#pragma unroll 4
        for (int k = 0; k < HD; ++k)
            acc = fmaf(h1[k], w2t[k * HD + t], acc);
        h2[t] = acc * ow[t];
    }
    __syncthreads();
    if (t < 64) {
        float s = h2[t] + h2[t + 64] + h2[t + 128];
#pragma unroll
        for (int d = 1; d < 64; d <<= 1) s += __shfl_xor(s, d);
        if (t == 0) out[g] = s + ob[0];
    }
}

extern "C" void kernel_launch(void* const* d_in, const int* in_sizes, int n_in,
                              void* d_out, int out_size, void* d_ws, size_t ws_size,
                              hipStream_t stream)
{
    const float* x       = (const float*)d_in[0];
    const int*   ei      = (const int*)d_in[1];
    const int*   batch   = (const int*)d_in[2];
    const float* w_rel0  = (const float*)d_in[4];
    const float* b_rel0  = (const float*)d_in[5];
    const float* w_root0 = (const float*)d_in[6];
    const float* w_rel   = (const float*)d_in[7];
    const float* b_rel   = (const float*)d_in[8];
    const float* w_root  = (const float*)d_in[9];
    const float* bn_g    = (const float*)d_in[10];
    const float* bn_b    = (const float*)d_in[11];
    const float* hw1     = (const float*)d_in[12];
    const float* hb1     = (const float*)d_in[13];
    const float* hw2     = (const float*)d_in[14];
    const float* hb2     = (const float*)d_in[15];
    const float* ow      = (const float*)d_in[16];
    const float* ob      = (const float*)d_in[17];
    float* out = (float*)d_out;

    const int N = in_sizes[0] / FD0;
    const int E = in_sizes[1] / 2;
    const int* src = ei;
    const int* dst = ei + E;
    const int M = idiv(N, 256);

    char* ws = (char*)d_ws;
    size_t off = 0;
    u16*   xb   = (u16*)(ws + off);   off += (size_t)N * FD0 * 2;
    u16*   h    = (u16*)(ws + off);   off += (size_t)N * HD * 2;
    u16*   aggb = (u16*)(ws + off);   off += (size_t)N * HD * 2;
    u16*   wp0  = (u16*)(ws + off);   off += (size_t)HD * 2 * FD0 * 2;
    u16*   wp123= (u16*)(ws + off);   off += (size_t)3 * HD * 2 * HD * 2;
    off = (off + 15) & ~(size_t)15;
    float* w1t = (float*)(ws + off); off += (size_t)HD * HD * 4;
    float* w2t = (float*)(ws + off); off += (size_t)HD * HD * 4;
    long long* statsq4 = (long long*)(ws + off); off += 4 * 2 * HD * sizeof(long long);
    int*   gsumq  = (int*)(ws + off); off += (size_t)NG * HD * 4;   // adjacent to statsq4
    int*   rowptr = (int*)(ws + off); off += (size_t)(N + 1) * 4;
    int*   deg    = (int*)(ws + off); off += (size_t)N * 4;
    int*   psum   = (int*)(ws + off); off += (size_t)M * 4;
    int*   eidx   = (int*)(ws + off); off += (size_t)E * 4;

    const dim3 b256(256), b512(512), b192(192);

    // ---- prep: convert, pack+transpose, zero stats+gsum, CSR build
    convert_bf16<<<idiv(N * FD0 / 4, 256), b256, 0, stream>>>(x, xb, N * FD0 / 4);
    pack_fuse<<<idiv(HD * 2 * FD0 + 3 * HD * 2 * HD + 2 * HD * HD, 256), b256, 0,
                stream>>>(w_rel0, w_root0, w_rel, w_root, hw1, hw2,
                          wp0, wp123, w1t, w2t);
    hipMemsetAsync(statsq4, 0, 4 * 2 * HD * sizeof(long long) + (size_t)NG * HD * 4,
                   stream);
    hipMemsetAsync(deg, 0, (size_t)N * sizeof(int), stream);
    hist_kernel<<<idiv(E, 256), b256, 0, stream>>>(dst, deg, E);
    scan_partial<<<M, b256, 0, stream>>>(deg, psum, N);
    scan_small<<<1, b256, 0, stream>>>(psum, M);
    scan_expand<<<M, b256, 0, stream>>>(deg, psum, rowptr, N, E);  // deg -> cursor
    fill_kernel<<<idiv(E, 256), b256, 0, stream>>>(src, dst, deg, eidx, E);

    // ---- layer 0 (K=128+128): raw x features
    gather_kernel<FD0, false><<<N, b256, 0, stream>>>(
        xb, rowptr, eidx, aggb, N, nullptr, nullptr, nullptr);
    gemm_mfma<FD0, FD0, false><<<idiv(N, 256), b512, 0, stream>>>(
        aggb, xb, wp0, b_rel0, h, statsq4, nullptr, nullptr, nullptr, N);

    // ---- layers 1..3 (K=192+192): BN+ReLU fused into consumers; gemm in-place
    for (int i = 0; i < 3; ++i) {
        const long long* sin  = statsq4 + (size_t)i * 2 * HD;
        long long*       sout = statsq4 + (size_t)(i + 1) * 2 * HD;
        const float* g = bn_g + (size_t)i * HD;
        const float* b = bn_b + (size_t)i * HD;
        gather_kernel<HD, true><<<N, b256, 0, stream>>>(
            h, rowptr, eidx, aggb, N, sin, g, b);
        gemm_mfma<HD, HD, true><<<idiv(N, 256), b512, 0, stream>>>(
            aggb, h, wp123 + (size_t)i * HD * 2 * HD,
            b_rel + (size_t)i * HD, h, sout, sin, g, b, N);
    }

    // ---- pool partials (BN(3) fused) + tiny head
    pool_partial<<<idiv(N, 256), b192, 0, stream>>>(
        h, batch, gsumq, N, statsq4 + 3 * 2 * (size_t)HD,
        bn_g + 3 * (size_t)HD, bn_b + 3 * (size_t)HD);
    head_kernel<<<NG, b192, 0, stream>>>(gsumq, batch, N, w1t, hb1, w2t, hb2,
                                         ow, ob, out);
}

// Round 17
// 404.499 us; speedup vs baseline: 2.2510x; 1.1821x over previous
//
#include <hip/hip_runtime.h>

#define HD 192
#define FD0 128
#define NG 256
#define BNEPS 1e-5f

#define STAT_S  1048576.0f        // 2^20 fixed-point scale for BN stats
#define STAT_IS (1.0f / 1048576.0f)
#define POOL_S  65536.0f          // 2^16 fixed-point scale for pooling
#define POOL_IS (1.0f / 65536.0f)

typedef unsigned short u16;
typedef __attribute__((ext_vector_type(8))) short bf16x8;
typedef __attribute__((ext_vector_type(4))) float f32x4;

static inline int idiv(int a, int b) { return (a + b - 1) / b; }

__device__ __forceinline__ float b2f(u16 u) {
    unsigned int v = ((unsigned int)u) << 16;
    return __builtin_bit_cast(float, v);
}
__device__ __forceinline__ float b2f_lo(unsigned int u) {
    return __builtin_bit_cast(float, u << 16);
}
__device__ __forceinline__ float b2f_hi(unsigned int u) {
    return __builtin_bit_cast(float, u & 0xffff0000u);
}
__device__ __forceinline__ u16 f2b(float f) {
    unsigned int x = __builtin_bit_cast(unsigned int, f);
    return (u16)((x + 0x7FFFu + ((x >> 16) & 1u)) >> 16);   // RNE
}

// BN scale/shift from fixed-point sum/sumsq (statsq layout: [HD sum][HD sumsq])
__device__ __forceinline__ void bn_params(const long long* __restrict__ statsq,
    const float* __restrict__ gamma, const float* __restrict__ beta,
    int N, int c, float& sc, float& sh)
{
    const float inv = 1.0f / (float)N;
    const float sum = (float)statsq[c] * STAT_IS;
    const float sq  = (float)statsq[HD + c] * STAT_IS;
    const float mu  = sum * inv;
    const float var = sq * inv - mu * mu;
    const float s   = gamma[c] * rsqrtf(var + BNEPS);
    sc = s; sh = beta[c] - mu * s;
}

// async global->LDS, 16B per lane; LDS dest = uniform base + lane*16
__device__ __forceinline__ void async_cp16(const void* g, void* l) {
    __builtin_amdgcn_global_load_lds(
        (const __attribute__((address_space(1))) unsigned int*)g,
        (__attribute__((address_space(3))) unsigned int*)l, 16, 0, 0);
}

// ---------------- x fp32 -> bf16 ----------------
__global__ __launch_bounds__(256) void convert_bf16(const float* __restrict__ in,
                                                    u16* __restrict__ out, int n4)
{
    const int i = blockIdx.x * 256 + threadIdx.x;
    if (i >= n4) return;
    const float4 v = ((const float4*)in)[i];
    u16 o[4] = { f2b(v.x), f2b(v.y), f2b(v.z), f2b(v.w) };
    ((ushort4*)out)[i] = *(ushort4*)o;
}

// ------- pack [Wr | Wt] bf16, MFMA-frag chunk order: [chunk][f12][kg][c][j] ---
__device__ __forceinline__ void pack_one(const float* __restrict__ wr,
    const float* __restrict__ wt, u16* __restrict__ out, int K, int idx)
{
    const int j  = idx & 7;
    const int t  = idx >> 3;
    const int c  = t & 15;
    const int kg = (t >> 4) & 3;
    const int rest = t >> 6;
    const int fglob = rest % 12;
    const int chunk = rest / 12;
    const int col = fglob * 16 + c;
    const int k   = chunk * 32 + kg * 8 + j;
    const float v = (k < K) ? wr[(size_t)col * K + k] : wt[(size_t)col * K + (k - K)];
    out[idx] = f2b(v);
}

// all weight packs + head transposes in ONE launch
__global__ __launch_bounds__(256) void pack_fuse(const float* __restrict__ wr0,
    const float* __restrict__ wt0, const float* __restrict__ w_rel,
    const float* __restrict__ w_root, const float* __restrict__ hw1,
    const float* __restrict__ hw2, u16* __restrict__ wp0,
    u16* __restrict__ wp123, float* __restrict__ w1t, float* __restrict__ w2t)
{
    const int T0 = HD * 2 * FD0;     // 49152
    const int T1 = HD * 2 * HD;      // 73728
    const int TW = HD * HD;          // 36864
    int idx = blockIdx.x * 256 + threadIdx.x;
    if (idx < T0) { pack_one(wr0, wt0, wp0, FD0, idx); return; }
    idx -= T0;
    if (idx < 3 * T1) {
        const int li = idx / T1;
        const int r  = idx - li * T1;
        pack_one(w_rel + (size_t)li * HD * HD, w_root + (size_t)li * HD * HD,
                 wp123 + (size_t)li * T1, HD, r);
        return;
    }
    idx -= 3 * T1;
    if (idx >= 2 * TW) return;
    const float* w = (idx < TW) ? hw1 : hw2;
    float*       o = (idx < TW) ? w1t : w2t;
    const int r = (idx < TW) ? idx : idx - TW;
    const int t = r % HD, k = r / HD;
    o[r] = w[(size_t)t * HD + k];
}

// ---------------- CSR build ----------------
__global__ __launch_bounds__(256) void hist_kernel(const int* __restrict__ dst,
                                                   int* __restrict__ deg, int E)
{
    const int e = blockIdx.x * 256 + threadIdx.x;
    if (e < E) atomicAdd(&deg[dst[e]], 1);
}

__global__ __launch_bounds__(256) void scan_partial(const int* __restrict__ deg,
                                                    int* __restrict__ psum, int N)
{
    __shared__ int s[256];
    const int t = threadIdx.x;
    const int i = blockIdx.x * 256 + t;
    s[t] = (i < N) ? deg[i] : 0;
    __syncthreads();
    for (int off = 128; off > 0; off >>= 1) {
        if (t < off) s[t] += s[t + off];
        __syncthreads();
    }
    if (t == 0) psum[blockIdx.x] = s[0];
}

__global__ __launch_bounds__(256) void scan_small(int* __restrict__ psum, int M)
{
    __shared__ int s[256];
    const int t = threadIdx.x;
    s[t] = (t < M) ? psum[t] : 0;
    __syncthreads();
    for (int off = 1; off < 256; off <<= 1) {
        const int u = (t >= off) ? s[t - off] : 0;
        __syncthreads();
        s[t] += u;
        __syncthreads();
    }
    if (t < M) psum[t] = (t == 0) ? 0 : s[t - 1];
}

// writes rowptr AND re-writes deg as the fill cursor (absolute base)
__global__ __launch_bounds__(256) void scan_expand(int* __restrict__ deg,
    const int* __restrict__ psum, int* __restrict__ rowptr, int N, int E)
{
    __shared__ int s[256];
    const int t = threadIdx.x;
    const int i = blockIdx.x * 256 + t;
    const int v = (i < N) ? deg[i] : 0;
    s[t] = v;
    __syncthreads();
    for (int off = 1; off < 256; off <<= 1) {
        const int u = (t >= off) ? s[t - off] : 0;
        __syncthreads();
        s[t] += u;
        __syncthreads();
    }
    if (i < N) {
        const int base = psum[blockIdx.x] + s[t] - v;   // exclusive
        rowptr[i] = base;
        deg[i]    = base;                                // cursor
    }
    if (i == N - 1) rowptr[N] = E;
}

__global__ __launch_bounds__(256) void fill_kernel(const int* __restrict__ src,
    const int* __restrict__ dst, int* __restrict__ cursor,
    int* __restrict__ eidx, int E)
{
    const int e = blockIdx.x * 256 + threadIdx.x;
    if (e >= E) return;
    const int p = atomicAdd(&cursor[dst[e]], 1);
    eidx[p] = src[e];
}

// ------- layer-0 gather (FD=128, no BN): full-lane, uint2/lane, 4-edge ILP ----
__global__ __launch_bounds__(256) void gather128(
    const u16* __restrict__ hsrc, const int* __restrict__ rowptr,
    const int* __restrict__ eidx, u16* __restrict__ aggb, int N)
{
    const int t    = threadIdx.x;
    const int lane = t & 63;
    const int half = lane >> 5;
    const int g    = lane & 31;           // 32 lanes x 4 shorts = 128
    const int n    = blockIdx.x * 4 + (t >> 6);
    if (n >= N) return;
    const int beg = rowptr[n], end = rowptr[n + 1];

    float acc[4] = {0.f, 0.f, 0.f, 0.f};

    auto consume = [&](uint2 v) {
        acc[0] += b2f_lo(v.x); acc[1] += b2f_hi(v.x);
        acc[2] += b2f_lo(v.y); acc[3] += b2f_hi(v.y);
    };

    int j = beg + half;
    for (; j + 6 < end; j += 8) {         // 4 edges in flight per lane
        const int s0 = eidx[j],     s1 = eidx[j + 2];
        const int s2 = eidx[j + 4], s3 = eidx[j + 6];
        const uint2 v0 = *(const uint2*)(hsrc + (size_t)s0 * FD0 + g * 4);
        const uint2 v1 = *(const uint2*)(hsrc + (size_t)s1 * FD0 + g * 4);
        const uint2 v2 = *(const uint2*)(hsrc + (size_t)s2 * FD0 + g * 4);
        const uint2 v3 = *(const uint2*)(hsrc + (size_t)s3 * FD0 + g * 4);
        consume(v0); consume(v1); consume(v2); consume(v3);
    }
    for (; j < end; j += 2)
        consume(*(const uint2*)(hsrc + (size_t)eidx[j] * FD0 + g * 4));

#pragma unroll
    for (int i = 0; i < 4; ++i) acc[i] += __shfl_xor(acc[i], 32);

    if (half == 0) {
        u16 ov[4];
#pragma unroll
        for (int i = 0; i < 4; ++i) ov[i] = f2b(acc[i]);
        *(uint2*)(aggb + (size_t)n * FD0 + g * 4) = *(uint2*)ov;
    }
}

// ------- CSR gather (FD=192) with fused BN+ReLU; wave/node; uint4; 4-edge ILP -
__global__ __launch_bounds__(256) void gather192(
    const u16* __restrict__ hsrc, const int* __restrict__ rowptr,
    const int* __restrict__ eidx, u16* __restrict__ aggb, int N,
    const long long* __restrict__ statsq, const float* __restrict__ gamma,
    const float* __restrict__ beta)
{
    constexpr int OCT = HD / 8;       // 24
    __shared__ float scs[HD], shs[HD];
    const int t = threadIdx.x;
    if (t < HD) {
        float sc, sh;
        bn_params(statsq, gamma, beta, N, t, sc, sh);
        scs[t] = sc; shs[t] = sh;
    }
    __syncthreads();
    const int lane = t & 63;
    const int half = lane >> 5;
    const int o    = lane & 31;
    const int n    = blockIdx.x * 4 + (t >> 6);
    if (n >= N) return;
    const bool act = (o < OCT);
    const int beg = rowptr[n], end = rowptr[n + 1];

    float scr[8], shr[8];
    if (act) {
#pragma unroll
        for (int i = 0; i < 8; ++i) { scr[i] = scs[o * 8 + i]; shr[i] = shs[o * 8 + i]; }
    }

    float acc[8];
#pragma unroll
    for (int i = 0; i < 8; ++i) acc[i] = 0.f;

    auto consume = [&](uint4 v) {
        const u16* pu = (const u16*)&v;
#pragma unroll
        for (int i = 0; i < 8; ++i)
            acc[i] += fmaxf(0.f, fmaf(b2f(pu[i]), scr[i], shr[i]));
    };

    int j = beg + half;
    for (; j + 6 < end; j += 8) {         // 4 edges in flight per lane
        const int s0 = eidx[j],     s1 = eidx[j + 2];
        const int s2 = eidx[j + 4], s3 = eidx[j + 6];
        if (act) {
            const uint4 v0 = *(const uint4*)(hsrc + (size_t)s0 * HD + o * 8);
            const uint4 v1 = *(const uint4*)(hsrc + (size_t)s1 * HD + o * 8);
            const uint4 v2 = *(const uint4*)(hsrc + (size_t)s2 * HD + o * 8);
            const uint4 v3 = *(const uint4*)(hsrc + (size_t)s3 * HD + o * 8);
            consume(v0); consume(v1); consume(v2); consume(v3);
        }
    }
    for (; j < end; j += 2) {
        const int s0 = eidx[j];
        if (act) consume(*(const uint4*)(hsrc + (size_t)s0 * HD + o * 8));
    }
#pragma unroll
    for (int i = 0; i < 8; ++i) acc[i] += __shfl_xor(acc[i], 32);

    if (half == 0 && act) {
        u16 ov[8];
#pragma unroll
        for (int i = 0; i < 8; ++i) ov[i] = f2b(acc[i]);
        *(uint4*)(aggb + (size_t)n * HD + o * 8) = *(uint4*)ov;
    }
}

// -------- MFMA GEMM: 256 thr / 4 waves; block = 128 rows x 192 cols ----------
// B panel staged in TWO K-halves (LDS = HD*KC/2 shorts -> 2-3 blocks/CU, grid
// covers all CUs); ring-4 A prefetch across halves; BN+ReLU fused onto A2.
// In-place safe: each wave reads only rows it later writes.
template<int K1, int K2, bool BN>
__global__ __launch_bounds__(256, 1) void gemm_mfma(
    const u16* __restrict__ A1, const u16* A2,
    const u16* __restrict__ Wb, const float* __restrict__ bias,
    u16* Hout, long long* __restrict__ statsq_out,
    const long long* __restrict__ statsq_in, const float* __restrict__ gamma,
    const float* __restrict__ beta, int N)
{
    constexpr int KC  = K1 + K2;
    constexpr int NC  = KC / 32;
    constexpr int NCH = NC / 2;           // chunks per K-half
    constexpr int NC1 = K1 / 32;
    __shared__ u16 bsh[HD * (KC / 2)];    // 73.7KB (KC=384) / 49.2KB (KC=256)
    __shared__ float scs[K2], shs[K2];

    const int tid  = threadIdx.x;
    const int wave = tid >> 6, lane = tid & 63;
    const int c = lane & 15, kg = lane >> 4;
    const int row0 = blockIdx.x * 128 + wave * 32;

    auto stage = [&](int hf) {            // stage one K-half linearly
        constexpr int NST = (HD * (KC / 2)) / (256 * 8);
        const u16* wsrc = Wb + (size_t)hf * (HD * (KC / 2)) + tid * 8;
        u16* ldst = bsh + tid * 8;
#pragma unroll
        for (int i = 0; i < NST; ++i)
            async_cp16(wsrc + i * 2048, ldst + i * 2048);
    };

    stage(0);
    if (BN) {
        if (tid < K2) {
            float sc, sh;
            bn_params(statsq_in, gamma, beta, N, tid, sc, sh);
            scs[tid] = sc; shs[tid] = sh;
        }
    }

    int arc[2];
#pragma unroll
    for (int m = 0; m < 2; ++m) {
        const int r = row0 + m * 16 + c;
        arc[m] = r < N ? r : N - 1;
    }

    f32x4 acc[2][12];
#pragma unroll
    for (int m = 0; m < 2; ++m)
#pragma unroll
        for (int f = 0; f < 12; ++f) acc[m][f] = (f32x4){0.f, 0.f, 0.f, 0.f};

    auto aload = [&](int ch, bf16x8* d) {
#pragma unroll
        for (int m = 0; m < 2; ++m) {
            const u16* p = (ch < NC1)
                ? (A1 + (size_t)arc[m] * K1 + ch * 32 + kg * 8)
                : (A2 + (size_t)arc[m] * K2 + (ch - NC1) * 32 + kg * 8);
            d[m] = *(const bf16x8*)p;
        }
    };

    auto bn_xform = [&](int ch, bf16x8* a) {
        if (BN && ch >= NC1) {
            const int k0 = (ch - NC1) * 32 + kg * 8;
            const float4 s0 = *(const float4*)&scs[k0];
            const float4 s1 = *(const float4*)&scs[k0 + 4];
            const float4 h0 = *(const float4*)&shs[k0];
            const float4 h1 = *(const float4*)&shs[k0 + 4];
            const float scv[8] = {s0.x,s0.y,s0.z,s0.w,s1.x,s1.y,s1.z,s1.w};
            const float shv[8] = {h0.x,h0.y,h0.z,h0.w,h1.x,h1.y,h1.z,h1.w};
#pragma unroll
            for (int m = 0; m < 2; ++m) {
                const u16* pa = (const u16*)&a[m];
                u16 tv[8];
#pragma unroll
                for (int i = 0; i < 8; ++i)
                    tv[i] = f2b(fmaxf(0.f, fmaf(b2f(pa[i]), scv[i], shv[i])));
                a[m] = *(bf16x8*)tv;
            }
        }
    };

    bf16x8 ring[4][2];
#pragma unroll
    for (int p = 0; p < 4; ++p)
        if (p < NC) aload(p, ring[p]);

    __syncthreads();      // drains K-half-0 staging; BN tables visible

#pragma unroll
    for (int ch = 0; ch < NCH; ++ch) {    // K-half 0
        bf16x8 a[2] = { ring[ch & 3][0], ring[ch & 3][1] };
        if (ch + 4 < NC) aload(ch + 4, ring[ch & 3]);
        bn_xform(ch, a);
#pragma unroll
        for (int f = 0; f < 12; ++f) {
            const bf16x8 b = *(const bf16x8*)&bsh[ch * 6144 + f * 512 + kg * 128 + c * 8];
            acc[0][f] = __builtin_amdgcn_mfma_f32_16x16x32_bf16(a[0], b, acc[0][f], 0, 0, 0);
            acc[1][f] = __builtin_amdgcn_mfma_f32_16x16x32_bf16(a[1], b, acc[1][f], 0, 0, 0);
        }
    }

    __syncthreads();      // all waves done reading K-half-0
    stage(1);
    __syncthreads();      // K-half-1 staged (barrier drains vmcnt)

#pragma unroll
    for (int ch = NCH; ch < NC; ++ch) {   // K-half 1
        bf16x8 a[2] = { ring[ch & 3][0], ring[ch & 3][1] };
        if (ch + 4 < NC) aload(ch + 4, ring[ch & 3]);
        bn_xform(ch, a);
#pragma unroll
        for (int f = 0; f < 12; ++f) {
            const bf16x8 b = *(const bf16x8*)&bsh[(ch - NCH) * 6144 + f * 512 + kg * 128 + c * 8];
            acc[0][f] = __builtin_amdgcn_mfma_f32_16x16x32_bf16(a[0], b, acc[0][f], 0, 0, 0);
            acc[1][f] = __builtin_amdgcn_mfma_f32_16x16x32_bf16(a[1], b, acc[1][f], 0, 0, 0);
        }
    }

    // ---- epilogue: bias + store + BN partial sums ----
    float s1v[12], s2v[12];
#pragma unroll
    for (int f = 0; f < 12; ++f) { s1v[f] = 0.f; s2v[f] = 0.f; }

#pragma unroll
    for (int f = 0; f < 12; ++f) {
        const int col = f * 16 + c;
        const float bv = bias[col];
#pragma unroll
        for (int m = 0; m < 2; ++m)
#pragma unroll
            for (int r = 0; r < 4; ++r) {
                const int orow = row0 + m * 16 + kg * 4 + r;
                if (orow < N) {
                    const float v = acc[m][f][r] + bv;
                    s1v[f] += v;
                    s2v[f] += v * v;
                    Hout[(size_t)orow * HD + col] = f2b(v);
                }
            }
    }
#pragma unroll
    for (int f = 0; f < 12; ++f) {
        s1v[f] += __shfl_xor(s1v[f], 16); s1v[f] += __shfl_xor(s1v[f], 32);
        s2v[f] += __shfl_xor(s2v[f], 16); s2v[f] += __shfl_xor(s2v[f], 32);
    }
    __syncthreads();                       // all waves done with bsh
    float* red = (float*)bsh;              // reuse panel LDS: 2 x 4 x 192 floats
    if (kg == 0) {
#pragma unroll
        for (int f = 0; f < 12; ++f) {
            red[wave * HD + f * 16 + c]            = s1v[f];
            red[4 * HD + wave * HD + f * 16 + c]   = s2v[f];
        }
    }
    __syncthreads();
    if (tid < HD) {
        float a1 = 0.f, a2 = 0.f;
#pragma unroll
        for (int w = 0; w < 4; ++w) {
            a1 += red[w * HD + tid];
            a2 += red[4 * HD + w * HD + tid];
        }
        atomicAdd((unsigned long long*)&statsq_out[tid],
                  (unsigned long long)(long long)llrintf(a1 * STAT_S));
        atomicAdd((unsigned long long*)&statsq_out[HD + tid],
                  (unsigned long long)(long long)llrintf(a2 * STAT_S));
    }
}

// ------- parallel mean-pool partials with fused BN+ReLU -----------------------
__global__ __launch_bounds__(192) void pool_partial(const u16* __restrict__ h,
    const int* __restrict__ batch, int* __restrict__ gsumq, int N,
    const long long* __restrict__ statsq, const float* __restrict__ gamma,
    const float* __restrict__ beta)
{
    __shared__ float scs[HD], shs[HD];
    const int t = threadIdx.x;
    {
        float sc, sh;
        bn_params(statsq, gamma, beta, N, t, sc, sh);
        scs[t] = sc; shs[t] = sh;
    }
    __syncthreads();
    const int rl  = t / 24;        // 0..7
    const int oct = t % 24;        // 0..23
    const int r0  = blockIdx.x * 256;
    const int rend = (r0 + 256 < N) ? r0 + 256 : N;

    float scr[8], shr[8];
#pragma unroll
    for (int i = 0; i < 8; ++i) { scr[i] = scs[oct * 8 + i]; shr[i] = shs[oct * 8 + i]; }

    float facc[8];
#pragma unroll
    for (int i = 0; i < 8; ++i) facc[i] = 0.f;
    int cur = -1;

    for (int r = r0 + rl; r < rend; r += 8) {
        const int b = batch[r];
        if (b != cur) {
            if (cur >= 0) {
                int* q = gsumq + (size_t)cur * HD + oct * 8;
#pragma unroll
                for (int i = 0; i < 8; ++i)
                    atomicAdd(&q[i], __float2int_rn(facc[i] * POOL_S));
            }
#pragma unroll
            for (int i = 0; i < 8; ++i) facc[i] = 0.f;
            cur = b;
        }
        const uint4 pv = *(const uint4*)(h + (size_t)r * HD + oct * 8);
        const u16* pu = (const u16*)&pv;
#pragma unroll
        for (int i = 0; i < 8; ++i)
            facc[i] += fmaxf(0.f, fmaf(b2f(pu[i]), scr[i], shr[i]));
    }
    if (cur >= 0) {
        int* q = gsumq + (size_t)cur * HD + oct * 8;
#pragma unroll
        for (int i = 0; i < 8; ++i)
            atomicAdd(&q[i], __float2int_rn(facc[i] * POOL_S));
    }
}

// ------- MLP head: gv from fixed-point pool sums; coalesced weights -------
__global__ __launch_bounds__(192) void head_kernel(
    const int* __restrict__ gsumq, const int* __restrict__ batch, int N,
    const float* __restrict__ w1t, const float* __restrict__ b1,
    const float* __restrict__ w2t, const float* __restrict__ b2,
    const float* __restrict__ ow, const float* __restrict__ ob,
    float* __restrict__ out)
{
    __shared__ float gv[HD];
    __shared__ float h1[HD];
    __shared__ float h2[HD];
    const int g = blockIdx.x;
    const int t = threadIdx.x;

    int lo = 0, hi = N;
    while (lo < hi) { int m = (lo + hi) >> 1; if (batch[m] < g) lo = m + 1; else hi = m; }
    const int start = lo;
    hi = N;
    while (lo < hi) { int m = (lo + hi) >> 1; if (batch[m] < g + 1) lo = m + 1; else hi = m; }
    const int end = lo;
    const float cnt = fmaxf((float)(end - start), 1.0f);

    gv[t] = (float)gsumq[(size_t)g * HD + t] * POOL_IS / cnt;
    __syncthreads();
    {
        float acc = b1[t];
#pragma unroll 4
        for (int k = 0; k < HD; ++k)
            acc = fmaf(gv[k], w1t[k * HD + t], acc);
        h1[t] = fmaxf(acc, 0.f);
    }
    __syncthreads();
    {
        float acc = b2[t];
#pragma unroll 4
        for (int k = 0; k < HD; ++k)
            acc = fmaf(h1[k], w2t[k * HD + t], acc);
        h2[t] = acc * ow[t];
    }
    __syncthreads();
    if (t < 64) {
        float s = h2[t] + h2[t + 64] + h2[t + 128];
#pragma unroll
        for (int d = 1; d < 64; d <<= 1) s += __shfl_xor(s, d);
        if (t == 0) out[g] = s + ob[0];
    }
}

extern "C" void kernel_launch(void* const* d_in, const int* in_sizes, int n_in,
                              void* d_out, int out_size, void* d_ws, size_t ws_size,
                              hipStream_t stream)
{
    const float* x       = (const float*)d_in[0];
    const int*   ei      = (const int*)d_in[1];
    const int*   batch   = (const int*)d_in[2];
    const float* w_rel0  = (const float*)d_in[4];
    const float* b_rel0  = (const float*)d_in[5];
    const float* w_root0 = (const float*)d_in[6];
    const float* w_rel   = (const float*)d_in[7];
    const float* b_rel   = (const float*)d_in[8];
    const float* w_root  = (const float*)d_in[9];
    const float* bn_g    = (const float*)d_in[10];
    const float* bn_b    = (const float*)d_in[11];
    const float* hw1     = (const float*)d_in[12];
    const float* hb1     = (const float*)d_in[13];
    const float* hw2     = (const float*)d_in[14];
    const float* hb2     = (const float*)d_in[15];
    const float* ow      = (const float*)d_in[16];
    const float* ob      = (const float*)d_in[17];
    float* out = (float*)d_out;

    const int N = in_sizes[0] / FD0;
    const int E = in_sizes[1] / 2;
    const int* src = ei;
    const int* dst = ei + E;
    const int M = idiv(N, 256);

    char* ws = (char*)d_ws;
    size_t off = 0;
    u16*   xb   = (u16*)(ws + off);   off += (size_t)N * FD0 * 2;
    u16*   h    = (u16*)(ws + off);   off += (size_t)N * HD * 2;
    u16*   aggb = (u16*)(ws + off);   off += (size_t)N * HD * 2;
    u16*   wp0  = (u16*)(ws + off);   off += (size_t)HD * 2 * FD0 * 2;
    u16*   wp123= (u16*)(ws + off);   off += (size_t)3 * HD * 2 * HD * 2;
    off = (off + 15) & ~(size_t)15;
    float* w1t = (float*)(ws + off); off += (size_t)HD * HD * 4;
    float* w2t = (float*)(ws + off); off += (size_t)HD * HD * 4;
    long long* statsq4 = (long long*)(ws + off); off += 4 * 2 * HD * sizeof(long long);
    int*   gsumq  = (int*)(ws + off); off += (size_t)NG * HD * 4;   // adjacent to statsq4
    int*   rowptr = (int*)(ws + off); off += (size_t)(N + 1) * 4;
    int*   deg    = (int*)(ws + off); off += (size_t)N * 4;
    int*   psum   = (int*)(ws + off); off += (size_t)M * 4;
    int*   eidx   = (int*)(ws + off); off += (size_t)E * 4;

    const dim3 b256(256), b192(192);

    // ---- prep: convert, pack+transpose, zero stats+gsum, CSR build
    convert_bf16<<<idiv(N * FD0 / 4, 256), b256, 0, stream>>>(x, xb, N * FD0 / 4);
    pack_fuse<<<idiv(HD * 2 * FD0 + 3 * HD * 2 * HD + 2 * HD * HD, 256), b256, 0,
                stream>>>(w_rel0, w_root0, w_rel, w_root, hw1, hw2,
                          wp0, wp123, w1t, w2t);
    hipMemsetAsync(statsq4, 0, 4 * 2 * HD * sizeof(long long) + (size_t)NG * HD * 4,
                   stream);
    hipMemsetAsync(deg, 0, (size_t)N * sizeof(int), stream);
    hist_kernel<<<idiv(E, 256), b256, 0, stream>>>(dst, deg, E);
    scan_partial<<<M, b256, 0, stream>>>(deg, psum, N);
    scan_small<<<1, b256, 0, stream>>>(psum, M);
    scan_expand<<<M, b256, 0, stream>>>(deg, psum, rowptr, N, E);  // deg -> cursor
    fill_kernel<<<idiv(E, 256), b256, 0, stream>>>(src, dst, deg, eidx, E);

    // ---- layer 0 (K=128+128): raw x features
    gather128<<<idiv(N, 4), b256, 0, stream>>>(xb, rowptr, eidx, aggb, N);
    gemm_mfma<FD0, FD0, false><<<idiv(N, 128), b256, 0, stream>>>(
        aggb, xb, wp0, b_rel0, h, statsq4, nullptr, nullptr, nullptr, N);

    // ---- layers 1..3 (K=192+192): BN+ReLU fused into consumers; gemm in-place
    for (int i = 0; i < 3; ++i) {
        const long long* sin  = statsq4 + (size_t)i * 2 * HD;
        long long*       sout = statsq4 + (size_t)(i + 1) * 2 * HD;
        const float* g = bn_g + (size_t)i * HD;
        const float* b = bn_b + (size_t)i * HD;
        gather192<<<idiv(N, 4), b256, 0, stream>>>(
            h, rowptr, eidx, aggb, N, sin, g, b);
        gemm_mfma<HD, HD, true><<<idiv(N, 128), b256, 0, stream>>>(
            aggb, h, wp123 + (size_t)i * HD * 2 * HD,
            b_rel + (size_t)i * HD, h, sout, sin, g, b, N);
    }

    // ---- pool partials (BN(3) fused) + tiny head
    pool_partial<<<idiv(N, 256), b192, 0, stream>>>(
        h, batch, gsumq, N, statsq4 + 3 * 2 * (size_t)HD,
        bn_g + 3 * (size_t)HD, bn_b + 3 * (size_t)HD);
    head_kernel<<<NG, b192, 0, stream>>>(gsumq, batch, N, w1t, hb1, w2t, hb2,
                                         ow, ob, out);
}

// Round 20
// 390.589 us; speedup vs baseline: 2.3312x; 1.0356x over previous
//
#include <hip/hip_runtime.h>

#define HD 192
#define FD0 128
#define NG 256
#define BNEPS 1e-5f

#define STAT_S  1048576.0f        // 2^20 fixed-point scale for BN stats
#define STAT_IS (1.0f / 1048576.0f)
#define POOL_S  65536.0f          // 2^16 fixed-point scale for pooling
#define POOL_IS (1.0f / 65536.0f)

typedef unsigned short u16;
typedef __attribute__((ext_vector_type(8))) short bf16x8;
typedef __attribute__((ext_vector_type(4))) float f32x4;

static inline int idiv(int a, int b) { return (a + b - 1) / b; }

__device__ __forceinline__ float b2f(u16 u) {
    unsigned int v = ((unsigned int)u) << 16;
    return __builtin_bit_cast(float, v);
}
__device__ __forceinline__ float b2f_lo(unsigned int u) {
    return __builtin_bit_cast(float, u << 16);
}
__device__ __forceinline__ float b2f_hi(unsigned int u) {
    return __builtin_bit_cast(float, u & 0xffff0000u);
}
__device__ __forceinline__ u16 f2b(float f) {
    unsigned int x = __builtin_bit_cast(unsigned int, f);
    return (u16)((x + 0x7FFFu + ((x >> 16) & 1u)) >> 16);   // RNE
}

// BN scale/shift from fixed-point sum/sumsq (statsq layout: [HD sum][HD sumsq])
__device__ __forceinline__ void bn_params(const long long* __restrict__ statsq,
    const float* __restrict__ gamma, const float* __restrict__ beta,
    int N, int c, float& sc, float& sh)
{
    const float inv = 1.0f / (float)N;
    const float sum = (float)statsq[c] * STAT_IS;
    const float sq  = (float)statsq[HD + c] * STAT_IS;
    const float mu  = sum * inv;
    const float var = sq * inv - mu * mu;
    const float s   = gamma[c] * rsqrtf(var + BNEPS);
    sc = s; sh = beta[c] - mu * s;
}

// async global->LDS, 16B per lane; LDS dest = uniform base + lane*16
__device__ __forceinline__ void async_cp16(const void* g, void* l) {
    __builtin_amdgcn_global_load_lds(
        (const __attribute__((address_space(1))) unsigned int*)g,
        (__attribute__((address_space(3))) unsigned int*)l, 16, 0, 0);
}

// ---------------- x fp32 -> bf16 ----------------
__global__ __launch_bounds__(256) void convert_bf16(const float* __restrict__ in,
                                                    u16* __restrict__ out, int n4)
{
    const int i = blockIdx.x * 256 + threadIdx.x;
    if (i >= n4) return;
    const float4 v = ((const float4*)in)[i];
    u16 o[4] = { f2b(v.x), f2b(v.y), f2b(v.z), f2b(v.w) };
    ((ushort4*)out)[i] = *(ushort4*)o;
}

// ------- pack [Wr | Wt] bf16, MFMA-frag chunk order: [chunk][f12][kg][c][j] ---
__device__ __forceinline__ void pack_one(const float* __restrict__ wr,
    const float* __restrict__ wt, u16* __restrict__ out, int K, int idx)
{
    const int j  = idx & 7;
    const int t  = idx >> 3;
    const int c  = t & 15;
    const int kg = (t >> 4) & 3;
    const int rest = t >> 6;
    const int fglob = rest % 12;
    const int chunk = rest / 12;
    const int col = fglob * 16 + c;
    const int k   = chunk * 32 + kg * 8 + j;
    const float v = (k < K) ? wr[(size_t)col * K + k] : wt[(size_t)col * K + (k - K)];
    out[idx] = f2b(v);
}

// all weight packs + head transposes in ONE launch
__global__ __launch_bounds__(256) void pack_fuse(const float* __restrict__ wr0,
    const float* __restrict__ wt0, const float* __restrict__ w_rel,
    const float* __restrict__ w_root, const float* __restrict__ hw1,
    const float* __restrict__ hw2, u16* __restrict__ wp0,
    u16* __restrict__ wp123, float* __restrict__ w1t, float* __restrict__ w2t)
{
    const int T0 = HD * 2 * FD0;     // 49152
    const int T1 = HD * 2 * HD;      // 73728
    const int TW = HD * HD;          // 36864
    int idx = blockIdx.x * 256 + threadIdx.x;
    if (idx < T0) { pack_one(wr0, wt0, wp0, FD0, idx); return; }
    idx -= T0;
    if (idx < 3 * T1) {
        const int li = idx / T1;
        const int r  = idx - li * T1;
        pack_one(w_rel + (size_t)li * HD * HD, w_root + (size_t)li * HD * HD,
                 wp123 + (size_t)li * T1, HD, r);
        return;
    }
    idx -= 3 * T1;
    if (idx >= 2 * TW) return;
    const float* w = (idx < TW) ? hw1 : hw2;
    float*       o = (idx < TW) ? w1t : w2t;
    const int r = (idx < TW) ? idx : idx - TW;
    const int t = r % HD, k = r / HD;
    o[r] = w[(size_t)t * HD + k];
}

// ---------------- CSR build ----------------
__global__ __launch_bounds__(256) void hist_kernel(const int* __restrict__ dst,
                                                   int* __restrict__ deg, int E)
{
    const int e = blockIdx.x * 256 + threadIdx.x;
    if (e < E) atomicAdd(&deg[dst[e]], 1);
}

__global__ __launch_bounds__(256) void scan_partial(const int* __restrict__ deg,
                                                    int* __restrict__ psum, int N)
{
    __shared__ int s[256];
    const int t = threadIdx.x;
    const int i = blockIdx.x * 256 + t;
    s[t] = (i < N) ? deg[i] : 0;
    __syncthreads();
    for (int off = 128; off > 0; off >>= 1) {
        if (t < off) s[t] += s[t + off];
        __syncthreads();
    }
    if (t == 0) psum[blockIdx.x] = s[0];
}

__global__ __launch_bounds__(256) void scan_small(int* __restrict__ psum, int M)
{
    __shared__ int s[256];
    const int t = threadIdx.x;
    s[t] = (t < M) ? psum[t] : 0;
    __syncthreads();
    for (int off = 1; off < 256; off <<= 1) {
        const int u = (t >= off) ? s[t - off] : 0;
        __syncthreads();
        s[t] += u;
        __syncthreads();
    }
    if (t < M) psum[t] = (t == 0) ? 0 : s[t - 1];
}

// writes rowptr AND re-writes deg as the fill cursor (absolute base)
__global__ __launch_bounds__(256) void scan_expand(int* __restrict__ deg,
    const int* __restrict__ psum, int* __restrict__ rowptr, int N, int E)
{
    __shared__ int s[256];
    const int t = threadIdx.x;
    const int i = blockIdx.x * 256 + t;
    const int v = (i < N) ? deg[i] : 0;
    s[t] = v;
    __syncthreads();
    for (int off = 1; off < 256; off <<= 1) {
        const int u = (t >= off) ? s[t - off] : 0;
        __syncthreads();
        s[t] += u;
        __syncthreads();
    }
    if (i < N) {
        const int base = psum[blockIdx.x] + s[t] - v;   // exclusive
        rowptr[i] = base;
        deg[i]    = base;                                // cursor
    }
    if (i == N - 1) rowptr[N] = E;
}

__global__ __launch_bounds__(256) void fill_kernel(const int* __restrict__ src,
    const int* __restrict__ dst, int* __restrict__ cursor,
    int* __restrict__ eidx, int E)
{
    const int e = blockIdx.x * 256 + threadIdx.x;
    if (e >= E) return;
    const int p = atomicAdd(&cursor[dst[e]], 1);
    eidx[p] = src[e];
}

// ------- layer-0 gather (FD=128): full-lane, uint2/lane, 4-edge ILP ----------
// (proven in R17) wave per node; half-wave per edge parity; direct eidx loads.
__global__ __launch_bounds__(256) void gather128(
    const u16* __restrict__ hsrc, const int* __restrict__ rowptr,
    const int* __restrict__ eidx, u16* __restrict__ aggb, int N)
{
    const int t    = threadIdx.x;
    const int lane = t & 63;
    const int half = lane >> 5;
    const int g    = lane & 31;           // 32 lanes x 4 shorts = 128
    const int n    = blockIdx.x * 4 + (t >> 6);
    if (n >= N) return;
    const int beg = rowptr[n], end = rowptr[n + 1];

    float acc[4] = {0.f, 0.f, 0.f, 0.f};

    auto consume = [&](uint2 v) {
        acc[0] += b2f_lo(v.x); acc[1] += b2f_hi(v.x);
        acc[2] += b2f_lo(v.y); acc[3] += b2f_hi(v.y);
    };

    int j = beg + half;
    for (; j + 6 < end; j += 8) {         // 4 edges in flight per lane
        const int s0 = eidx[j],     s1 = eidx[j + 2];
        const int s2 = eidx[j + 4], s3 = eidx[j + 6];
        const uint2 v0 = *(const uint2*)(hsrc + (size_t)s0 * FD0 + g * 4);
        const uint2 v1 = *(const uint2*)(hsrc + (size_t)s1 * FD0 + g * 4);
        const uint2 v2 = *(const uint2*)(hsrc + (size_t)s2 * FD0 + g * 4);
        const uint2 v3 = *(const uint2*)(hsrc + (size_t)s3 * FD0 + g * 4);
        consume(v0); consume(v1); consume(v2); consume(v3);
    }
    for (; j < end; j += 2)
        consume(*(const uint2*)(hsrc + (size_t)eidx[j] * FD0 + g * 4));

#pragma unroll
    for (int i = 0; i < 4; ++i) acc[i] += __shfl_xor(acc[i], 32);

    if (half == 0) {
        u16 ov[4];
#pragma unroll
        for (int i = 0; i < 4; ++i) ov[i] = f2b(acc[i]);
        *(uint2*)(aggb + (size_t)n * FD0 + g * 4) = *(uint2*)ov;
    }
}

// ------- CSR gather (FD=192), fused BN+ReLU; direct eidx loads (proven R14) --
__global__ __launch_bounds__(256) void gather192(
    const u16* __restrict__ hsrc, const int* __restrict__ rowptr,
    const int* __restrict__ eidx, u16* __restrict__ aggb, int N,
    const long long* __restrict__ statsq, const float* __restrict__ gamma,
    const float* __restrict__ beta)
{
    constexpr int OCT = HD / 8;       // 24
    __shared__ float scs[HD], shs[HD];
    const int t = threadIdx.x;
    if (t < HD) {
        float sc, sh;
        bn_params(statsq, gamma, beta, N, t, sc, sh);
        scs[t] = sc; shs[t] = sh;
    }
    __syncthreads();
    const int lane = t & 63;
    const int half = lane >> 5;
    const int o    = lane & 31;
    const int n    = blockIdx.x * 4 + (t >> 6);
    if (n >= N) return;
    const bool act = (o < OCT);
    const int beg = rowptr[n], end = rowptr[n + 1];

    float scr[8], shr[8];
    if (act) {
#pragma unroll
        for (int i = 0; i < 8; ++i) { scr[i] = scs[o * 8 + i]; shr[i] = shs[o * 8 + i]; }
    }

    float acc[8];
#pragma unroll
    for (int i = 0; i < 8; ++i) acc[i] = 0.f;

    auto consume = [&](uint4 v) {
        const u16* pu = (const u16*)&v;
#pragma unroll
        for (int i = 0; i < 8; ++i)
            acc[i] += fmaxf(0.f, fmaf(b2f(pu[i]), scr[i], shr[i]));
    };

    int j = beg + half;
    for (; j + 6 < end; j += 8) {         // 4 edges in flight per lane
        const int s0 = eidx[j],     s1 = eidx[j + 2];
        const int s2 = eidx[j + 4], s3 = eidx[j + 6];
        if (act) {
            const uint4 v0 = *(const uint4*)(hsrc + (size_t)s0 * HD + o * 8);
            const uint4 v1 = *(const uint4*)(hsrc + (size_t)s1 * HD + o * 8);
            const uint4 v2 = *(const uint4*)(hsrc + (size_t)s2 * HD + o * 8);
            const uint4 v3 = *(const uint4*)(hsrc + (size_t)s3 * HD + o * 8);
            consume(v0); consume(v1); consume(v2); consume(v3);
        }
    }
    for (; j < end; j += 2) {
        const int s0 = eidx[j];
        if (act) consume(*(const uint4*)(hsrc + (size_t)s0 * HD + o * 8));
    }
#pragma unroll
    for (int i = 0; i < 8; ++i) acc[i] += __shfl_xor(acc[i], 32);

    if (half == 0 && act) {
        u16 ov[8];
#pragma unroll
        for (int i = 0; i < 8; ++i) ov[i] = f2b(acc[i]);
        *(uint4*)(aggb + (size_t)n * HD + o * 8) = *(uint4*)ov;
    }
}

// -------- MFMA GEMM: 512 thr / 8 waves; block = 256 rows x 192 cols ----------
// Full B panel resident in LDS (staged once, global_load_lds); K-loop fully
// unrolled with depth-4 A register prefetch ring; BN+ReLU fused onto A2 reads.
// In-place safe: each wave reads only rows it later writes. (proven R14)
template<int K1, int K2, bool BN>
__global__ __launch_bounds__(512, 1) void gemm_mfma(
    const u16* __restrict__ A1, const u16* A2,
    const u16* __restrict__ Wb, const float* __restrict__ bias,
    u16* Hout, long long* __restrict__ statsq_out,
    const long long* __restrict__ statsq_in, const float* __restrict__ gamma,
    const float* __restrict__ beta, int N)
{
    constexpr int KC  = K1 + K2;
    constexpr int NC  = KC / 32;
    constexpr int NC1 = K1 / 32;
    __shared__ u16 bsh[HD * KC];          // 98KB (KC=256) / 147KB (KC=384)
    __shared__ float scs[K2], shs[K2];

    const int tid  = threadIdx.x;
    const int wave = tid >> 6, lane = tid & 63;
    const int c = lane & 15, kg = lane >> 4;
    const int row0 = blockIdx.x * 256 + wave * 32;

    {   // stage whole panel linearly (512 thr x 16B = 8KB per iter)
        constexpr int NST = (HD * KC) / (512 * 8);
        const u16* wsrc = Wb + tid * 8;
        u16* ldst = bsh + tid * 8;
#pragma unroll
        for (int i = 0; i < NST; ++i)
            async_cp16(wsrc + i * 4096, ldst + i * 4096);
    }
    if (BN) {
        if (tid < K2) {
            float sc, sh;
            bn_params(statsq_in, gamma, beta, N, tid, sc, sh);
            scs[tid] = sc; shs[tid] = sh;
        }
    }

    int arc[2];
#pragma unroll
    for (int m = 0; m < 2; ++m) {
        const int r = row0 + m * 16 + c;
        arc[m] = r < N ? r : N - 1;
    }

    f32x4 acc[2][12];
#pragma unroll
    for (int m = 0; m < 2; ++m)
#pragma unroll
        for (int f = 0; f < 12; ++f) acc[m][f] = (f32x4){0.f, 0.f, 0.f, 0.f};

    auto aload = [&](int ch, bf16x8* d) {
#pragma unroll
        for (int m = 0; m < 2; ++m) {
            const u16* p = (ch < NC1)
                ? (A1 + (size_t)arc[m] * K1 + ch * 32 + kg * 8)
                : (A2 + (size_t)arc[m] * K2 + (ch - NC1) * 32 + kg * 8);
            d[m] = *(const bf16x8*)p;
        }
    };

    bf16x8 ring[4][2];
#pragma unroll
    for (int p = 0; p < 4; ++p)
        if (p < NC) aload(p, ring[p]);

    __syncthreads();      // drains global_load_lds staging; scs/shs visible

#pragma unroll
    for (int ch = 0; ch < NC; ++ch) {
        bf16x8 a[2] = { ring[ch & 3][0], ring[ch & 3][1] };
        if (ch + 4 < NC) aload(ch + 4, ring[ch & 3]);   // refill slot
        if (BN && ch >= NC1) {                          // BN+ReLU on root frags
            const int k0 = (ch - NC1) * 32 + kg * 8;
            const float4 s0 = *(const float4*)&scs[k0];
            const float4 s1 = *(const float4*)&scs[k0 + 4];
            const float4 h0 = *(const float4*)&shs[k0];
            const float4 h1 = *(const float4*)&shs[k0 + 4];
            const float scv[8] = {s0.x,s0.y,s0.z,s0.w,s1.x,s1.y,s1.z,s1.w};
            const float shv[8] = {h0.x,h0.y,h0.z,h0.w,h1.x,h1.y,h1.z,h1.w};
#pragma unroll
            for (int m = 0; m < 2; ++m) {
                const u16* pa = (const u16*)&a[m];
                u16 tv[8];
#pragma unroll
                for (int i = 0; i < 8; ++i)
                    tv[i] = f2b(fmaxf(0.f, fmaf(b2f(pa[i]), scv[i], shv[i])));
                a[m] = *(bf16x8*)tv;
            }
        }
#pragma unroll
        for (int f = 0; f < 12; ++f) {
            const bf16x8 b = *(const bf16x8*)&bsh[ch * 6144 + f * 512 + kg * 128 + c * 8];
            acc[0][f] = __builtin_amdgcn_mfma_f32_16x16x32_bf16(a[0], b, acc[0][f], 0, 0, 0);
            acc[1][f] = __builtin_amdgcn_mfma_f32_16x16x32_bf16(a[1], b, acc[1][f], 0, 0, 0);
        }
    }

    // ---- epilogue: bias + store + BN partial sums ----
    float s1v[12], s2v[12];
#pragma unroll
    for (int f = 0; f < 12; ++f) { s1v[f] = 0.f; s2v[f] = 0.f; }

#pragma unroll
    for (int f = 0; f < 12; ++f) {
        const int col = f * 16 + c;
        const float bv = bias[col];
#pragma unroll
        for (int m = 0; m < 2; ++m)
#pragma unroll
            for (int r = 0; r < 4; ++r) {
                const int orow = row0 + m * 16 + kg * 4 + r;
                if (orow < N) {
                    const float v = acc[m][f][r] + bv;
                    s1v[f] += v;
                    s2v[f] += v * v;
                    Hout[(size_t)orow * HD + col] = f2b(v);
                }
            }
    }
#pragma unroll
    for (int f = 0; f < 12; ++f) {
        s1v[f] += __shfl_xor(s1v[f], 16); s1v[f] += __shfl_xor(s1v[f], 32);
        s2v[f] += __shfl_xor(s2v[f], 16); s2v[f] += __shfl_xor(s2v[f], 32);
    }
    __syncthreads();                       // all waves done with bsh
    float* red = (float*)bsh;              // reuse panel LDS: 2 x 8 x 192 floats
    if (kg == 0) {
#pragma unroll
        for (int f = 0; f < 12; ++f) {
            red[wave * HD + f * 16 + c]            = s1v[f];
            red[8 * HD + wave * HD + f * 16 + c]   = s2v[f];
        }
    }
    __syncthreads();
    if (tid < HD) {
        float a1 = 0.f, a2 = 0.f;
#pragma unroll
        for (int w = 0; w < 8; ++w) {
            a1 += red[w * HD + tid];
            a2 += red[8 * HD + w * HD + tid];
        }
        atomicAdd((unsigned long long*)&statsq_out[tid],
                  (unsigned long long)(long long)llrintf(a1 * STAT_S));
        atomicAdd((unsigned long long*)&statsq_out[HD + tid],
                  (unsigned long long)(long long)llrintf(a2 * STAT_S));
    }
}

// ------- parallel mean-pool partials with fused BN+ReLU -----------------------
__global__ __launch_bounds__(192) void pool_partial(const u16* __restrict__ h,
    const int* __restrict__ batch, int* __restrict__ gsumq, int N,
    const long long* __restrict__ statsq, const float* __restrict__ gamma,
    const float* __restrict__ beta)
{
    __shared__ float scs[HD], shs[HD];
    const int t = threadIdx.x;
    {
        float sc, sh;
        bn_params(statsq, gamma, beta, N, t, sc, sh);
        scs[t] = sc; shs[t] = sh;
    }
    __syncthreads();
    const int rl  = t / 24;        // 0..7
    const int oct = t % 24;        // 0..23
    const int r0  = blockIdx.x * 256;
    const int rend = (r0 + 256 < N) ? r0 + 256 : N;

    float scr[8], shr[8];
#pragma unroll
    for (int i = 0; i < 8; ++i) { scr[i] = scs[oct * 8 + i]; shr[i] = shs[oct * 8 + i]; }

    float facc[8];
#pragma unroll
    for (int i = 0; i < 8; ++i) facc[i] = 0.f;
    int cur = -1;

    for (int r = r0 + rl; r < rend; r += 8) {
        const int b = batch[r];
        if (b != cur) {
            if (cur >= 0) {
                int* q = gsumq + (size_t)cur * HD + oct * 8;
#pragma unroll
                for (int i = 0; i < 8; ++i)
                    atomicAdd(&q[i], __float2int_rn(facc[i] * POOL_S));
            }
#pragma unroll
            for (int i = 0; i < 8; ++i) facc[i] = 0.f;
            cur = b;
        }
        const uint4 pv = *(const uint4*)(h + (size_t)r * HD + oct * 8);
        const u16* pu = (const u16*)&pv;
#pragma unroll
        for (int i = 0; i < 8; ++i)
            facc[i] += fmaxf(0.f, fmaf(b2f(pu[i]), scr[i], shr[i]));
    }
    if (cur >= 0) {
        int* q = gsumq + (size_t)cur * HD + oct * 8;
#pragma unroll
        for (int i = 0; i < 8; ++i)
            atomicAdd(&q[i], __float2int_rn(facc[i] * POOL_S));
    }
}

// ------- MLP head: gv from fixed-point pool sums; coalesced weights -------
__global__ __launch_bounds__(192) void head_kernel(
    const int* __restrict__ gsumq, const int* __restrict__ batch, int N,
    const float* __restrict__ w1t, const float* __restrict__ b1,
    const float* __restrict__ w2t, const float* __restrict__ b2,
    const float* __restrict__ ow, const float* __restrict__ ob,
    float* __restrict__ out)
{
    __shared__ float gv[HD];
    __shared__ float h1[HD];
    __shared__ float h2[HD];
    const int g = blockIdx.x;
    const int t = threadIdx.x;

    int lo = 0, hi = N;
    while (lo < hi) { int m = (lo + hi) >> 1; if (batch[m] < g) lo = m + 1; else hi = m; }
    const int start = lo;
    hi = N;
    while (lo < hi) { int m = (lo + hi) >> 1; if (batch[m] < g + 1) lo = m + 1; else hi = m; }
    const int end = lo;
    const float cnt = fmaxf((float)(end - start), 1.0f);

    gv[t] = (float)gsumq[(size_t)g * HD + t] * POOL_IS / cnt;
    __syncthreads();
    {
        float acc = b1[t];
#pragma unroll 4
        for (int k = 0; k < HD; ++k)
            acc = fmaf(gv[k], w1t[k * HD + t], acc);
        h1[t] = fmaxf(acc, 0.f);
    }
    __syncthreads();
    {
        float acc = b2[t];
#pragma unroll 4
        for (int k = 0; k < HD; ++k)
            acc = fmaf(h1[k], w2t[k * HD + t], acc);
        h2[t] = acc * ow[t];
    }
    __syncthreads();
    if (t < 64) {
        float s = h2[t] + h2[t + 64] + h2[t + 128];
#pragma unroll
        for (int d = 1; d < 64; d <<= 1) s += __shfl_xor(s, d);
        if (t == 0) out[g] = s + ob[0];
    }
}

extern "C" void kernel_launch(void* const* d_in, const int* in_sizes, int n_in,
                              void* d_out, int out_size, void* d_ws, size_t ws_size,
                              hipStream_t stream)
{
    const float* x       = (const float*)d_in[0];
    const int*   ei      = (const int*)d_in[1];
    const int*   batch   = (const int*)d_in[2];
    const float* w_rel0  = (const float*)d_in[4];
    const float* b_rel0  = (const float*)d_in[5];
    const float* w_root0 = (const float*)d_in[6];
    const float* w_rel   = (const float*)d_in[7];
    const float* b_rel   = (const float*)d_in[8];
    const float* w_root  = (const float*)d_in[9];
    const float* bn_g    = (const float*)d_in[10];
    const float* bn_b    = (const float*)d_in[11];
    const float* hw1     = (const float*)d_in[12];
    const float* hb1     = (const float*)d_in[13];
    const float* hw2     = (const float*)d_in[14];
    const float* hb2     = (const float*)d_in[15];
    const float* ow      = (const float*)d_in[16];
    const float* ob      = (const float*)d_in[17];
    float* out = (float*)d_out;

    const int N = in_sizes[0] / FD0;
    const int E = in_sizes[1] / 2;
    const int* src = ei;
    const int* dst = ei + E;
    const int M = idiv(N, 256);

    char* ws = (char*)d_ws;
    size_t off = 0;
    u16*   xb   = (u16*)(ws + off);   off += (size_t)N * FD0 * 2;
    u16*   h    = (u16*)(ws + off);   off += (size_t)N * HD * 2;
    u16*   aggb = (u16*)(ws + off);   off += (size_t)N * HD * 2;
    u16*   wp0  = (u16*)(ws + off);   off += (size_t)HD * 2 * FD0 * 2;
    u16*   wp123= (u16*)(ws + off);   off += (size_t)3 * HD * 2 * HD * 2;
    off = (off + 15) & ~(size_t)15;
    float* w1t = (float*)(ws + off); off += (size_t)HD * HD * 4;
    float* w2t = (float*)(ws + off); off += (size_t)HD * HD * 4;
    long long* statsq4 = (long long*)(ws + off); off += 4 * 2 * HD * sizeof(long long);
    int*   gsumq  = (int*)(ws + off); off += (size_t)NG * HD * 4;   // adjacent to statsq4
    int*   rowptr = (int*)(ws + off); off += (size_t)(N + 1) * 4;
    int*   deg    = (int*)(ws + off); off += (size_t)N * 4;
    int*   psum   = (int*)(ws + off); off += (size_t)M * 4;
    int*   eidx   = (int*)(ws + off); off += (size_t)E * 4;

    const dim3 b256(256), b512(512), b192(192);

    // ---- prep: convert, pack+transpose, zero stats+gsum, CSR build
    convert_bf16<<<idiv(N * FD0 / 4, 256), b256, 0, stream>>>(x, xb, N * FD0 / 4);
    pack_fuse<<<idiv(HD * 2 * FD0 + 3 * HD * 2 * HD + 2 * HD * HD, 256), b256, 0,
                stream>>>(w_rel0, w_root0, w_rel, w_root, hw1, hw2,
                          wp0, wp123, w1t, w2t);
    hipMemsetAsync(statsq4, 0, 4 * 2 * HD * sizeof(long long) + (size_t)NG * HD * 4,
                   stream);
    hipMemsetAsync(deg, 0, (size_t)N * sizeof(int), stream);
    hist_kernel<<<idiv(E, 256), b256, 0, stream>>>(dst, deg, E);
    scan_partial<<<M, b256, 0, stream>>>(deg, psum, N);
    scan_small<<<1, b256, 0, stream>>>(psum, M);
    scan_expand<<<M, b256, 0, stream>>>(deg, psum, rowptr, N, E);  // deg -> cursor
    fill_kernel<<<idiv(E, 256), b256, 0, stream>>>(src, dst, deg, eidx, E);

    // ---- layer 0 (K=128+128): raw x features
    gather128<<<idiv(N, 4), b256, 0, stream>>>(xb, rowptr, eidx, aggb, N);
    gemm_mfma<FD0, FD0, false><<<idiv(N, 256), b512, 0, stream>>>(
        aggb, xb, wp0, b_rel0, h, statsq4, nullptr, nullptr, nullptr, N);

    // ---- layers 1..3 (K=192+192): BN+ReLU fused into consumers; gemm in-place
    for (int i = 0; i < 3; ++i) {
        const long long* sin  = statsq4 + (size_t)i * 2 * HD;
        long long*       sout = statsq4 + (size_t)(i + 1) * 2 * HD;
        const float* g = bn_g + (size_t)i * HD;
        const float* b = bn_b + (size_t)i * HD;
        gather192<<<idiv(N, 4), b256, 0, stream>>>(
            h, rowptr, eidx, aggb, N, sin, g, b);
        gemm_mfma<HD, HD, true><<<idiv(N, 256), b512, 0, stream>>>(
            aggb, h, wp123 + (size_t)i * HD * 2 * HD,
            b_rel + (size_t)i * HD, h, sout, sin, g, b, N);
    }

    // ---- pool partials (BN(3) fused) + tiny head
    pool_partial<<<idiv(N, 256), b192, 0, stream>>>(
        h, batch, gsumq, N, statsq4 + 3 * 2 * (size_t)HD,
        bn_g + 3 * (size_t)HD, bn_b + 3 * (size_t)HD);
    head_kernel<<<NG, b192, 0, stream>>>(gsumq, batch, N, w1t, hb1, w2t, hb2,
                                         ow, ob, out);
}